// Round 5
// baseline (365.879 us; speedup 1.0000x reference)
//
#include <hip/hip_runtime.h>

// VMamba mixer forward, MI355X. fp32 + bf16-MFMA x_proj.
// Two-phase chunked selective scan: states-only pass (bf16 chunk states) ->
// bf16 prefix combine -> full recompute seeded with exact inter-chunk state.
// No ybuf read-modify-write, no cumdA fixup.

constexpr int DM   = 96;     // D_MODEL
constexpr int DI   = 192;    // D_INNER
constexpr int RK   = 6;      // DT_RANK
constexpr int NS   = 32;     // D_STATE (== HEAD_D)
constexpr int KD   = 4;      // directions
constexpr int HW   = 56;
constexpr int LT   = 3136;   // L = 56*56
constexpr int NB   = 8;      // batch
constexpr int NPOS = NB * LT;   // 25088
constexpr int NC   = 64;     // chunks per sequence
constexpr int CH   = 49;     // chunk length (64*49 = 3136)
constexpr int SEQ = NB * KD; // 32 sequences
constexpr int ELEM = RK * NS * NS;  // 6144 state elements per sequence
constexpr int NO   = 280;    // x_proj outputs (4*70)
constexpr int NOP  = 288;    // padded to 18 MFMA n-tiles

typedef __attribute__((ext_vector_type(8))) __bf16 bf16x8;
typedef __attribute__((ext_vector_type(4))) float f32x4;

__device__ __forceinline__ float siluf(float x) { return x / (1.f + __expf(-x)); }

__device__ __forceinline__ unsigned short f2bf(float f) {  // RNE, finite inputs
  unsigned int u = __float_as_uint(f);
  u = (u + 0x7fffu + ((u >> 16) & 1u)) >> 16;
  return (unsigned short)u;
}
__device__ __forceinline__ float bf2f(unsigned short h) {
  return __uint_as_float(((unsigned int)h) << 16);
}
__device__ __forceinline__ unsigned int pack2(float a, float b) {
  return (unsigned int)f2bf(a) | ((unsigned int)f2bf(b) << 16);
}

// sequence index l of direction k  ->  spatial position p (row-major h*56+w)
__device__ __forceinline__ int seq2pos(int k, int l) {
  int m = (k & 2) ? (LT - 1 - l) : l;
  return (k & 1) ? ((m % HW) * HW + m / HW) : m;
}

// ---------------- Kernel 1: in_proj + split + silu(z) ----------------
__global__ __launch_bounds__(384) void k_inproj(const float* __restrict__ x,
                                                const float* __restrict__ Wi,
                                                float* __restrict__ xi,
                                                float* __restrict__ zs) {
  const int PPB = 16;
  __shared__ float sx[PPB][DM];
  int p0 = blockIdx.x * PPB;
  int tid = threadIdx.x;
  for (int i = tid; i < PPB * DM; i += 384) sx[i / DM][i % DM] = x[p0 * DM + i];
  __syncthreads();
  int o = tid;  // output column 0..383
  float acc[PPB];
#pragma unroll
  for (int p = 0; p < PPB; p++) acc[p] = 0.f;
  const float* wr = Wi + o * DM;
  for (int kk = 0; kk < DM; kk++) {
    float w = wr[kk];
#pragma unroll
    for (int p = 0; p < PPB; p++) acc[p] += w * sx[p][kk];
  }
  if (o < DI) {
    for (int p = 0; p < PPB; p++) xi[(p0 + p) * DI + o] = acc[p];
  } else {
    int oz = o - DI;
    for (int p = 0; p < PPB; p++) zs[(p0 + p) * DI + oz] = siluf(acc[p]);
  }
}

// ---------------- Kernel 2: depthwise 3x3 conv + bias + silu (+bf16 copy) ----
__global__ void k_conv(const float* __restrict__ xi, const float* __restrict__ cw,
                       const float* __restrict__ cb, float* __restrict__ xc,
                       unsigned short* __restrict__ xcb) {
  int t = blockIdx.x * 256 + threadIdx.x;
  if (t >= NPOS * DI) return;
  int c = t % DI;
  int pos = t / DI;
  int p = pos % LT, b = pos / LT;
  int h = p / HW, w = p % HW;
  float acc = cb[c];
#pragma unroll
  for (int dh = 0; dh < 3; dh++) {
    int hh = h + dh - 1;
    if (hh < 0 || hh >= HW) continue;
#pragma unroll
    for (int dw = 0; dw < 3; dw++) {
      int ww = w + dw - 1;
      if (ww < 0 || ww >= HW) continue;
      acc += cw[(dh * 3 + dw) * DI + c] * xi[(b * LT + hh * HW + ww) * DI + c];
    }
  }
  float v = siluf(acc);
  xc[t] = v;
  xcb[t] = f2bf(v);
}

// ---------------- Kernel 2b: Wp -> bf16, padded to 288 rows ----------------
__global__ __launch_bounds__(256) void k_wprep(const float* __restrict__ Wp,
                                               unsigned short* __restrict__ Wpb) {
  int t = blockIdx.x * 256 + threadIdx.x;
  if (t >= NOP * DI) return;
  int o = t / DI;
  Wpb[t] = (o < NO) ? f2bf(Wp[t]) : (unsigned short)0;
}

// ---------------- Kernel 3: x_proj via bf16 MFMA + softplus/exp ----------------
__global__ __launch_bounds__(128) void k_xproj(const unsigned short* __restrict__ xcb,
                                               const unsigned short* __restrict__ Wpb,
                                               const float* __restrict__ A_logs,
                                               const float* __restrict__ dt_bias,
                                               float* __restrict__ dtb,
                                               float* __restrict__ dAb,
                                               float* __restrict__ Bsb,
                                               float* __restrict__ Csb) {
  int wid = threadIdx.x >> 6;
  int lane = threadIdx.x & 63;
  int pos0 = blockIdx.x * 32 + wid * 16;
  int lrow = lane & 15;   // A: position-in-tile, B: output-in-tile
  int lgrp = lane >> 4;   // k-group (8 bf16 each)
  bf16x8 a[6];
  const unsigned short* arow = xcb + (size_t)(pos0 + lrow) * DI + lgrp * 8;
#pragma unroll
  for (int ks = 0; ks < 6; ks++)
    a[ks] = *reinterpret_cast<const bf16x8*>(arow + ks * 32);
  f32x4 acc[18];
#pragma unroll
  for (int t = 0; t < 18; t++) acc[t] = (f32x4){0.f, 0.f, 0.f, 0.f};
  const unsigned short* brow = Wpb + (size_t)lrow * DI + lgrp * 8;
#pragma unroll
  for (int ks = 0; ks < 6; ks++) {
#pragma unroll
    for (int ot = 0; ot < 18; ot++) {
      bf16x8 bf = *reinterpret_cast<const bf16x8*>(brow + (size_t)ot * 16 * DI + ks * 32);
      acc[ot] = __builtin_amdgcn_mfma_f32_16x16x32_bf16(a[ks], bf, acc[ot], 0, 0, 0);
    }
  }
#pragma unroll
  for (int ot = 0; ot < 18; ot++) {
    int o = ot * 16 + lrow;
    if (o >= NO) continue;
    int k = o / 70, c = o % 70;
#pragma unroll
    for (int r = 0; r < 4; r++) {
      int pos = pos0 + lgrp * 4 + r;
      float v = acc[ot][r];
      int base = pos * KD + k;
      if (c < RK) {
        float bias = dt_bias[k * RK + c];
        float Av = -__expf(A_logs[k * RK + c]);
        float s = v + bias;
        float dtv = (s > 20.f) ? s : log1pf(__expf(s));
        dtb[base * RK + c] = dtv;
        dAb[base * RK + c] = __expf(dtv * Av);
      } else if (c < RK + NS) {
        Bsb[base * NS + (c - RK)] = v;
      } else {
        Csb[base * NS + (c - RK - NS)] = v;
      }
    }
  }
}

// ---------------- Kernel 4: states-only local scan ----------------
// block = 192 threads, thread = (r,d). 2048 blocks = (b,k,chunk).
__global__ __launch_bounds__(192) void k_scanA(const float* __restrict__ xc,
                                               const float* __restrict__ dtb,
                                               const float* __restrict__ dAb,
                                               const float* __restrict__ Bsb,
                                               unsigned short* __restrict__ Send,
                                               float* __restrict__ Pend) {
  int bi = blockIdx.x;
  int chunk = bi % NC;
  int k = (bi / NC) & 3;
  int b = bi / (NC * KD);
  int seq = b * KD + k;
  int tid = threadIdx.x;
  int r = tid >> 5, d = tid & 31;
  float S[NS];
#pragma unroll
  for (int n = 0; n < NS; n++) S[n] = 0.f;
  float cum = 1.f;
  int l0 = chunk * CH;
  for (int l = 0; l < CH; l++) {
    int p = seq2pos(k, l0 + l);
    int gbase = b * LT + p;
    int base = gbase * KD + k;          // block-uniform
    const f32x4* Bp = reinterpret_cast<const f32x4*>(Bsb + (size_t)base * NS);
    f32x4 bv[8];
#pragma unroll
    for (int i = 0; i < 8; i++) bv[i] = Bp[i];
    float dAr = dAb[base * RK + r];
    float dtr = dtb[base * RK + r];
    float xv = xc[gbase * DI + tid];
    float xdt = xv * dtr;
#pragma unroll
    for (int i = 0; i < 8; i++) {
#pragma unroll
      for (int j = 0; j < 4; j++) {
        int n = i * 4 + j;
        S[n] = S[n] * dAr + xdt * bv[i][j];
      }
    }
    cum *= dAr;
  }
  // store chunk-end state as bf16 (32 values = 4x uint4)
  unsigned int* dst = (unsigned int*)(Send + (size_t)(seq * NC + chunk) * ELEM + tid * NS);
#pragma unroll
  for (int i = 0; i < 16; i++) dst[i] = pack2(S[2 * i], S[2 * i + 1]);
  if (d == 0) Pend[(seq * NC + chunk) * RK + r] = cum;
}

// ---------------- Kernel 5: chunk-state combine (bf16 in-place excl. prefix) ----
// 98304 independent uint-packed pairs, chains of length NC.
__global__ __launch_bounds__(256) void k_scanB(unsigned int* __restrict__ Send32,
                                               const float* __restrict__ Pend) {
  const int EU = ELEM / 2;           // 3072 uints per (seq,chunk)
  int bi = blockIdx.x;               // 32 seqs * 12 uint-tiles
  int seq = bi / (EU / 256);
  int u = (bi % (EU / 256)) * 256 + threadIdx.x;
  int r = u >> 9;                    // element e = 2u, r = e>>10
  float run0 = 0.f, run1 = 0.f;
  for (int c = 0; c < NC; c++) {
    size_t idx = (size_t)(seq * NC + c) * EU + u;
    unsigned int v = Send32[idx];
    float t0 = bf2f((unsigned short)(v & 0xffff));
    float t1 = bf2f((unsigned short)(v >> 16));
    Send32[idx] = pack2(run0, run1);
    float pe = Pend[(seq * NC + c) * RK + r];
    run0 = run0 * pe + t0;
    run1 = run1 * pe + t1;
  }
}

// ---------------- Kernel 6: full scan recompute seeded with Sinit ----------------
__global__ __launch_bounds__(192) void k_scanD(const float* __restrict__ xc,
                                               const float* __restrict__ dtb,
                                               const float* __restrict__ dAb,
                                               const float* __restrict__ Bsb,
                                               const float* __restrict__ Csb,
                                               const float* __restrict__ Ds,
                                               const unsigned short* __restrict__ Sinit,
                                               float* __restrict__ ybuf) {
  int bi = blockIdx.x;
  int chunk = bi % NC;
  int k = (bi / NC) & 3;
  int b = bi / (NC * KD);
  int seq = b * KD + k;
  int tid = threadIdx.x;
  int r = tid >> 5, d = tid & 31;
  float S[NS];
  const unsigned int* sp = (const unsigned int*)(Sinit + (size_t)(seq * NC + chunk) * ELEM + tid * NS);
#pragma unroll
  for (int i = 0; i < 16; i++) {
    unsigned int v = sp[i];
    S[2 * i]     = bf2f((unsigned short)(v & 0xffff));
    S[2 * i + 1] = bf2f((unsigned short)(v >> 16));
  }
  float Dsv = Ds[(k * RK + r) * NS + d];
  int l0 = chunk * CH;
  for (int l = 0; l < CH; l++) {
    int p = seq2pos(k, l0 + l);
    int gbase = b * LT + p;
    int base = gbase * KD + k;          // block-uniform
    const f32x4* Bp = reinterpret_cast<const f32x4*>(Bsb + (size_t)base * NS);
    const f32x4* Cp = reinterpret_cast<const f32x4*>(Csb + (size_t)base * NS);
    f32x4 bv[8], cv[8];
#pragma unroll
    for (int i = 0; i < 8; i++) { bv[i] = Bp[i]; cv[i] = Cp[i]; }
    float dAr = dAb[base * RK + r];
    float dtr = dtb[base * RK + r];
    float xv = xc[gbase * DI + tid];
    float xdt = xv * dtr;
    float y = 0.f;
#pragma unroll
    for (int i = 0; i < 8; i++) {
#pragma unroll
      for (int j = 0; j < 4; j++) {
        int n = i * 4 + j;
        S[n] = S[n] * dAr + xdt * bv[i][j];
        y += S[n] * cv[i][j];
      }
    }
    ybuf[((size_t)(b * KD + k) * LT + p) * DI + tid] = y + xv * Dsv;
  }
}

// ---------------- Kernel 7: merge + LN + gelu + *silu(z) + out_proj ----------------
__global__ __launch_bounds__(192) void k_out(const float* __restrict__ ybuf,
                                             const float* __restrict__ zs,
                                             const float* __restrict__ ln_g,
                                             const float* __restrict__ ln_b,
                                             const float* __restrict__ Wo,
                                             float* __restrict__ out) {
  const int PP = 4;
  int pos0 = blockIdx.x * PP;
  int b = pos0 / LT, p0 = pos0 % LT;
  int tid = threadIdx.x;  // 0..191 = channel
  float v[PP], s1[PP], s2[PP];
#pragma unroll
  for (int q = 0; q < PP; q++) {
    float acc = 0.f;
#pragma unroll
    for (int k = 0; k < KD; k++) acc += ybuf[((size_t)(b * KD + k) * LT + p0 + q) * DI + tid];
    v[q] = acc; s1[q] = acc; s2[q] = acc * acc;
  }
#pragma unroll
  for (int off = 32; off; off >>= 1) {
#pragma unroll
    for (int q = 0; q < PP; q++) {
      s1[q] += __shfl_down(s1[q], off, 64);
      s2[q] += __shfl_down(s2[q], off, 64);
    }
  }
  __shared__ float rs1[3][PP], rs2[3][PP];
  int wave = tid >> 6, lane = tid & 63;
  if (lane == 0) {
#pragma unroll
    for (int q = 0; q < PP; q++) { rs1[wave][q] = s1[q]; rs2[wave][q] = s2[q]; }
  }
  __syncthreads();
  __shared__ float su[PP][DI];
  float g = ln_g[tid], be = ln_b[tid];
#pragma unroll
  for (int q = 0; q < PP; q++) {
    float mean = (rs1[0][q] + rs1[1][q] + rs1[2][q]) * (1.f / 192.f);
    float var = (rs2[0][q] + rs2[1][q] + rs2[2][q]) * (1.f / 192.f) - mean * mean;
    float rstd = rsqrtf(var + 1e-5f);
    float t = (v[q] - mean) * rstd * g + be;
    float ge = 0.5f * t * (1.f + erff(t * 0.70710678118f));
    su[q][tid] = ge * zs[(pos0 + q) * DI + tid];
  }
  __syncthreads();
  int o = tid % DM, half = tid / DM;
  const float* wr = Wo + o * DI + half * DM;
  float acc[PP];
#pragma unroll
  for (int q = 0; q < PP; q++) acc[q] = 0.f;
  for (int j = 0; j < DM; j++) {
    float w = wr[j];
#pragma unroll
    for (int q = 0; q < PP; q++) acc[q] += w * su[q][half * DM + j];
  }
  __shared__ float part[PP][DI];
#pragma unroll
  for (int q = 0; q < PP; q++) part[q][tid] = acc[q];
  __syncthreads();
  if (tid < DM) {
#pragma unroll
    for (int q = 0; q < PP; q++)
      out[(pos0 + q) * DM + tid] = part[q][tid] + part[q][tid + DM];
  }
}

extern "C" void kernel_launch(void* const* d_in, const int* in_sizes, int n_in,
                              void* d_out, int out_size, void* d_ws, size_t ws_size,
                              hipStream_t stream) {
  const float* x       = (const float*)d_in[0];
  const float* Wi      = (const float*)d_in[1];
  const float* cw      = (const float*)d_in[2];
  const float* cb      = (const float*)d_in[3];
  const float* Wp      = (const float*)d_in[4];
  const float* Ds      = (const float*)d_in[5];
  const float* A_logs  = (const float*)d_in[6];
  const float* dt_bias = (const float*)d_in[7];
  const float* ln_g    = (const float*)d_in[8];
  const float* ln_b    = (const float*)d_in[9];
  const float* Wo      = (const float*)d_in[10];
  float* out = (float*)d_out;

  float* ws = (float*)d_ws;
  float* xi    = ws;                       // NPOS*DI
  float* zs    = xi + (size_t)NPOS * DI;
  float* xc    = zs + (size_t)NPOS * DI;
  float* dtb   = xc + (size_t)NPOS * DI;   // NPOS*KD*RK
  float* dAb   = dtb + (size_t)NPOS * KD * RK;
  float* Bsb   = dAb + (size_t)NPOS * KD * RK;   // NPOS*KD*NS
  float* Csb   = Bsb + (size_t)NPOS * KD * NS;
  float* ybuf  = Csb + (size_t)NPOS * KD * NS;   // NB*KD*LT*DI
  unsigned short* Send = (unsigned short*)(ybuf + (size_t)NB * KD * LT * DI); // SEQ*NC*ELEM bf16
  float* Pend  = (float*)(Send + (size_t)SEQ * NC * ELEM);  // SEQ*NC*RK
  float* WpbF  = Pend + (size_t)SEQ * NC * RK;              // NOP*DI bf16
  // xcb (bf16 conv copy) aliases Send: dead before scanA writes Send.
  unsigned short* xcb = (unsigned short*)Send;
  unsigned short* Wpb = (unsigned short*)WpbF;

  k_inproj<<<NPOS / 16, 384, 0, stream>>>(x, Wi, xi, zs);
  k_conv<<<(NPOS * DI + 255) / 256, 256, 0, stream>>>(xi, cw, cb, xc, xcb);
  k_wprep<<<(NOP * DI + 255) / 256, 256, 0, stream>>>(Wp, Wpb);
  k_xproj<<<NPOS / 32, 128, 0, stream>>>(xcb, Wpb, A_logs, dt_bias, dtb, dAb, Bsb, Csb);
  k_scanA<<<NB * KD * NC, 192, 0, stream>>>(xc, dtb, dAb, Bsb, Send, Pend);
  k_scanB<<<SEQ * (ELEM / 512), 256, 0, stream>>>((unsigned int*)Send, Pend);
  k_scanD<<<NB * KD * NC, 192, 0, stream>>>(xc, dtb, dAb, Bsb, Csb, Ds, Send, ybuf);
  k_out<<<NPOS / 4, 192, 0, stream>>>(ybuf, zs, ln_g, ln_b, Wo, out);
}

// Round 6
// 340.659 us; speedup vs baseline: 1.0740x; 1.0740x over previous
//
#include <hip/hip_runtime.h>

// VMamba mixer forward, MI355X. fp32 + bf16-MFMA x_proj.
// Two-phase chunked selective scan with packed-fp32 (v_pk_fma_f32) inner
// loops and incremental position stepping (no per-step div/mod).

constexpr int DM   = 96;     // D_MODEL
constexpr int DI   = 192;    // D_INNER
constexpr int RK   = 6;      // DT_RANK
constexpr int NS   = 32;     // D_STATE (== HEAD_D)
constexpr int KD   = 4;      // directions
constexpr int HW   = 56;
constexpr int LT   = 3136;   // L = 56*56
constexpr int NB   = 8;      // batch
constexpr int NPOS = NB * LT;   // 25088
constexpr int NC   = 64;     // chunks per sequence
constexpr int CH   = 49;     // chunk length (64*49 = 3136)
constexpr int SEQ = NB * KD; // 32 sequences
constexpr int ELEM = RK * NS * NS;  // 6144 state elements per sequence
constexpr int NO   = 280;    // x_proj outputs (4*70)
constexpr int NOP  = 288;    // padded to 18 MFMA n-tiles

typedef __attribute__((ext_vector_type(8))) __bf16 bf16x8;
typedef __attribute__((ext_vector_type(4))) float f32x4;
typedef __attribute__((ext_vector_type(2))) float f32x2;

__device__ __forceinline__ float siluf(float x) { return x / (1.f + __expf(-x)); }

__device__ __forceinline__ unsigned short f2bf(float f) {  // RNE, finite inputs
  unsigned int u = __float_as_uint(f);
  u = (u + 0x7fffu + ((u >> 16) & 1u)) >> 16;
  return (unsigned short)u;
}
__device__ __forceinline__ float bf2f(unsigned short h) {
  return __uint_as_float(((unsigned int)h) << 16);
}
__device__ __forceinline__ unsigned int pack2(float a, float b) {
  return (unsigned int)f2bf(a) | ((unsigned int)f2bf(b) << 16);
}

// sequence index l of direction k  ->  spatial position p (row-major h*56+w)
__device__ __forceinline__ int seq2pos(int k, int l) {
  int m = (k & 2) ? (LT - 1 - l) : l;
  return (k & 1) ? ((m % HW) * HW + m / HW) : m;
}

// Incremental position walker: uniform per-step update, no div/mod.
struct PosWalk {
  int p, cnt, wlim, winc, wstep, wadj, wrst;
  __device__ __forceinline__ void init(int k, int l0) {
    p = seq2pos(k, l0);
    if (k == 0)      { cnt = 0;  wlim = -9; winc = 0;  wstep = 1;   wadj = 0;     wrst = 0;  }
    else if (k == 1) { cnt = l0 % HW; wlim = HW - 1; winc = 1; wstep = HW; wadj = -(LT - HW - 1); wrst = 0; }
    else if (k == 2) { cnt = 0;  wlim = -9; winc = 0;  wstep = -1;  wadj = 0;     wrst = 0;  }
    else             { cnt = (LT - 1 - l0) % HW; wlim = 0; winc = -1; wstep = -HW; wadj = LT - HW - 1; wrst = HW - 1; }
  }
  __device__ __forceinline__ void next() {
    bool wrap = (cnt == wlim);
    p += wrap ? wadj : wstep;
    cnt = wrap ? wrst : cnt + winc;
  }
};

// ---------------- Kernel 1: in_proj + split + silu(z) ----------------
__global__ __launch_bounds__(384) void k_inproj(const float* __restrict__ x,
                                                const float* __restrict__ Wi,
                                                float* __restrict__ xi,
                                                float* __restrict__ zs) {
  const int PPB = 16;
  __shared__ float sx[PPB][DM];
  int p0 = blockIdx.x * PPB;
  int tid = threadIdx.x;
  for (int i = tid; i < PPB * DM; i += 384) sx[i / DM][i % DM] = x[p0 * DM + i];
  __syncthreads();
  int o = tid;  // output column 0..383
  float acc[PPB];
#pragma unroll
  for (int p = 0; p < PPB; p++) acc[p] = 0.f;
  const float* wr = Wi + o * DM;
  for (int kk = 0; kk < DM; kk++) {
    float w = wr[kk];
#pragma unroll
    for (int p = 0; p < PPB; p++) acc[p] += w * sx[p][kk];
  }
  if (o < DI) {
    for (int p = 0; p < PPB; p++) xi[(p0 + p) * DI + o] = acc[p];
  } else {
    int oz = o - DI;
    for (int p = 0; p < PPB; p++) zs[(p0 + p) * DI + oz] = siluf(acc[p]);
  }
}

// ---------------- Kernel 2: depthwise 3x3 conv + bias + silu (+bf16 copy) ----
__global__ void k_conv(const float* __restrict__ xi, const float* __restrict__ cw,
                       const float* __restrict__ cb, float* __restrict__ xc,
                       unsigned short* __restrict__ xcb) {
  int t = blockIdx.x * 256 + threadIdx.x;
  if (t >= NPOS * DI) return;
  int c = t % DI;
  int pos = t / DI;
  int p = pos % LT, b = pos / LT;
  int h = p / HW, w = p % HW;
  float acc = cb[c];
#pragma unroll
  for (int dh = 0; dh < 3; dh++) {
    int hh = h + dh - 1;
    if (hh < 0 || hh >= HW) continue;
#pragma unroll
    for (int dw = 0; dw < 3; dw++) {
      int ww = w + dw - 1;
      if (ww < 0 || ww >= HW) continue;
      acc += cw[(dh * 3 + dw) * DI + c] * xi[(b * LT + hh * HW + ww) * DI + c];
    }
  }
  float v = siluf(acc);
  xc[t] = v;
  xcb[t] = f2bf(v);
}

// ---------------- Kernel 2b: Wp -> bf16, padded to 288 rows ----------------
__global__ __launch_bounds__(256) void k_wprep(const float* __restrict__ Wp,
                                               unsigned short* __restrict__ Wpb) {
  int t = blockIdx.x * 256 + threadIdx.x;
  if (t >= NOP * DI) return;
  int o = t / DI;
  Wpb[t] = (o < NO) ? f2bf(Wp[t]) : (unsigned short)0;
}

// ---------------- Kernel 3: x_proj via bf16 MFMA + softplus/exp ----------------
__global__ __launch_bounds__(128) void k_xproj(const unsigned short* __restrict__ xcb,
                                               const unsigned short* __restrict__ Wpb,
                                               const float* __restrict__ A_logs,
                                               const float* __restrict__ dt_bias,
                                               float* __restrict__ dtb,
                                               float* __restrict__ dAb,
                                               float* __restrict__ Bsb,
                                               float* __restrict__ Csb) {
  int wid = threadIdx.x >> 6;
  int lane = threadIdx.x & 63;
  int pos0 = blockIdx.x * 32 + wid * 16;
  int lrow = lane & 15;   // A: position-in-tile, B: output-in-tile
  int lgrp = lane >> 4;   // k-group (8 bf16 each)
  bf16x8 a[6];
  const unsigned short* arow = xcb + (size_t)(pos0 + lrow) * DI + lgrp * 8;
#pragma unroll
  for (int ks = 0; ks < 6; ks++)
    a[ks] = *reinterpret_cast<const bf16x8*>(arow + ks * 32);
  f32x4 acc[18];
#pragma unroll
  for (int t = 0; t < 18; t++) acc[t] = (f32x4){0.f, 0.f, 0.f, 0.f};
  const unsigned short* brow = Wpb + (size_t)lrow * DI + lgrp * 8;
#pragma unroll
  for (int ks = 0; ks < 6; ks++) {
#pragma unroll
    for (int ot = 0; ot < 18; ot++) {
      bf16x8 bf = *reinterpret_cast<const bf16x8*>(brow + (size_t)ot * 16 * DI + ks * 32);
      acc[ot] = __builtin_amdgcn_mfma_f32_16x16x32_bf16(a[ks], bf, acc[ot], 0, 0, 0);
    }
  }
#pragma unroll
  for (int ot = 0; ot < 18; ot++) {
    int o = ot * 16 + lrow;
    if (o >= NO) continue;
    int k = o / 70, c = o % 70;
#pragma unroll
    for (int r = 0; r < 4; r++) {
      int pos = pos0 + lgrp * 4 + r;
      float v = acc[ot][r];
      int base = pos * KD + k;
      if (c < RK) {
        float bias = dt_bias[k * RK + c];
        float Av = -__expf(A_logs[k * RK + c]);
        float s = v + bias;
        float dtv = (s > 20.f) ? s : log1pf(__expf(s));
        dtb[base * RK + c] = dtv;
        dAb[base * RK + c] = __expf(dtv * Av);
      } else if (c < RK + NS) {
        Bsb[base * NS + (c - RK)] = v;
      } else {
        Csb[base * NS + (c - RK - NS)] = v;
      }
    }
  }
}

// ---------------- Kernel 4: states-only local scan (packed fp32) ----------------
__global__ __launch_bounds__(192) void k_scanA(const float* __restrict__ xc,
                                               const float* __restrict__ dtb,
                                               const float* __restrict__ dAb,
                                               const float* __restrict__ Bsb,
                                               unsigned short* __restrict__ Send,
                                               float* __restrict__ Pend) {
  int bi = blockIdx.x;
  int chunk = bi % NC;
  int k = (bi / NC) & 3;
  int b = bi / (NC * KD);
  int seq = b * KD + k;
  int tid = threadIdx.x;
  int r = tid >> 5, d = tid & 31;
  f32x2 S2[16];
#pragma unroll
  for (int i = 0; i < 16; i++) S2[i] = (f32x2){0.f, 0.f};
  float cum = 1.f;
  PosWalk pw; pw.init(k, chunk * CH);
  const float* xp = xc + (size_t)b * LT * DI + tid;
  size_t cb0 = (size_t)b * LT * KD + k;
  for (int l = 0; l < CH; l++) {
    size_t base = cb0 + (size_t)pw.p * KD;      // block-uniform
    const f32x4* Bp = reinterpret_cast<const f32x4*>(Bsb + base * NS);
    f32x4 bv[8];
#pragma unroll
    for (int i = 0; i < 8; i++) bv[i] = Bp[i];
    float dAr = dAb[base * RK + r];
    float dtr = dtb[base * RK + r];
    float xv = xp[(size_t)pw.p * DI];
    float xdt = xv * dtr;
    f32x2 dA2 = {dAr, dAr}, xd2 = {xdt, xdt};
#pragma unroll
    for (int i = 0; i < 8; i++) {
      f32x2 bl = __builtin_shufflevector(bv[i], bv[i], 0, 1);
      f32x2 bh = __builtin_shufflevector(bv[i], bv[i], 2, 3);
      S2[2 * i]     = S2[2 * i] * dA2 + xd2 * bl;
      S2[2 * i + 1] = S2[2 * i + 1] * dA2 + xd2 * bh;
    }
    cum *= dAr;
    pw.next();
  }
  unsigned int* dst = (unsigned int*)(Send + (size_t)(seq * NC + chunk) * ELEM + tid * NS);
#pragma unroll
  for (int i = 0; i < 16; i++) dst[i] = pack2(S2[i][0], S2[i][1]);
  if (d == 0) Pend[(seq * NC + chunk) * RK + r] = cum;
}

// ---------------- Kernel 5: chunk-state combine (bf16 in-place excl. prefix) ----
__global__ __launch_bounds__(256) void k_scanB(unsigned int* __restrict__ Send32,
                                               const float* __restrict__ Pend) {
  const int EU = ELEM / 2;           // 3072 uints per (seq,chunk)
  int bi = blockIdx.x;               // 32 seqs * 12 uint-tiles
  int seq = bi / (EU / 256);
  int u = (bi % (EU / 256)) * 256 + threadIdx.x;
  int r = u >> 9;                    // element e = 2u, r = e>>10
  float run0 = 0.f, run1 = 0.f;
  for (int c = 0; c < NC; c++) {
    size_t idx = (size_t)(seq * NC + c) * EU + u;
    unsigned int v = Send32[idx];
    float t0 = bf2f((unsigned short)(v & 0xffff));
    float t1 = bf2f((unsigned short)(v >> 16));
    Send32[idx] = pack2(run0, run1);
    float pe = Pend[(seq * NC + c) * RK + r];
    run0 = run0 * pe + t0;
    run1 = run1 * pe + t1;
  }
}

// ---------------- Kernel 6: full scan recompute seeded with Sinit (packed) ----
__global__ __launch_bounds__(192) void k_scanD(const float* __restrict__ xc,
                                               const float* __restrict__ dtb,
                                               const float* __restrict__ dAb,
                                               const float* __restrict__ Bsb,
                                               const float* __restrict__ Csb,
                                               const float* __restrict__ Ds,
                                               const unsigned short* __restrict__ Sinit,
                                               float* __restrict__ ybuf) {
  int bi = blockIdx.x;
  int chunk = bi % NC;
  int k = (bi / NC) & 3;
  int b = bi / (NC * KD);
  int seq = b * KD + k;
  int tid = threadIdx.x;
  int r = tid >> 5, d = tid & 31;
  f32x2 S2[16];
  const unsigned int* sp = (const unsigned int*)(Sinit + (size_t)(seq * NC + chunk) * ELEM + tid * NS);
#pragma unroll
  for (int i = 0; i < 16; i++) {
    unsigned int v = sp[i];
    S2[i] = (f32x2){bf2f((unsigned short)(v & 0xffff)), bf2f((unsigned short)(v >> 16))};
  }
  float Dsv = Ds[(k * RK + r) * NS + d];
  PosWalk pw; pw.init(k, chunk * CH);
  const float* xp = xc + (size_t)b * LT * DI + tid;
  float* yb = ybuf + (size_t)seq * LT * DI + tid;
  size_t cb0 = (size_t)b * LT * KD + k;
  for (int l = 0; l < CH; l++) {
    size_t base = cb0 + (size_t)pw.p * KD;      // block-uniform
    const f32x4* Bp = reinterpret_cast<const f32x4*>(Bsb + base * NS);
    const f32x4* Cp = reinterpret_cast<const f32x4*>(Csb + base * NS);
    f32x4 bv[8], cv[8];
#pragma unroll
    for (int i = 0; i < 8; i++) { bv[i] = Bp[i]; cv[i] = Cp[i]; }
    float dAr = dAb[base * RK + r];
    float dtr = dtb[base * RK + r];
    float xv = xp[(size_t)pw.p * DI];
    float xdt = xv * dtr;
    f32x2 dA2 = {dAr, dAr}, xd2 = {xdt, xdt};
    f32x2 y2 = {0.f, 0.f};
#pragma unroll
    for (int i = 0; i < 8; i++) {
      f32x2 bl = __builtin_shufflevector(bv[i], bv[i], 0, 1);
      f32x2 bh = __builtin_shufflevector(bv[i], bv[i], 2, 3);
      f32x2 cl = __builtin_shufflevector(cv[i], cv[i], 0, 1);
      f32x2 ch = __builtin_shufflevector(cv[i], cv[i], 2, 3);
      S2[2 * i]     = S2[2 * i] * dA2 + xd2 * bl;
      y2 += S2[2 * i] * cl;
      S2[2 * i + 1] = S2[2 * i + 1] * dA2 + xd2 * bh;
      y2 += S2[2 * i + 1] * ch;
    }
    yb[(size_t)pw.p * DI] = y2[0] + y2[1] + xv * Dsv;
    pw.next();
  }
}

// ---------------- Kernel 7: merge + LN + gelu + *silu(z) + out_proj ----------------
__global__ __launch_bounds__(192) void k_out(const float* __restrict__ ybuf,
                                             const float* __restrict__ zs,
                                             const float* __restrict__ ln_g,
                                             const float* __restrict__ ln_b,
                                             const float* __restrict__ Wo,
                                             float* __restrict__ out) {
  const int PP = 4;
  int pos0 = blockIdx.x * PP;
  int b = pos0 / LT, p0 = pos0 % LT;
  int tid = threadIdx.x;  // 0..191 = channel
  float v[PP], s1[PP], s2[PP];
#pragma unroll
  for (int q = 0; q < PP; q++) {
    float acc = 0.f;
#pragma unroll
    for (int k = 0; k < KD; k++) acc += ybuf[((size_t)(b * KD + k) * LT + p0 + q) * DI + tid];
    v[q] = acc; s1[q] = acc; s2[q] = acc * acc;
  }
#pragma unroll
  for (int off = 32; off; off >>= 1) {
#pragma unroll
    for (int q = 0; q < PP; q++) {
      s1[q] += __shfl_down(s1[q], off, 64);
      s2[q] += __shfl_down(s2[q], off, 64);
    }
  }
  __shared__ float rs1[3][PP], rs2[3][PP];
  int wave = tid >> 6, lane = tid & 63;
  if (lane == 0) {
#pragma unroll
    for (int q = 0; q < PP; q++) { rs1[wave][q] = s1[q]; rs2[wave][q] = s2[q]; }
  }
  __syncthreads();
  __shared__ float su[PP][DI];
  float g = ln_g[tid], be = ln_b[tid];
#pragma unroll
  for (int q = 0; q < PP; q++) {
    float mean = (rs1[0][q] + rs1[1][q] + rs1[2][q]) * (1.f / 192.f);
    float var = (rs2[0][q] + rs2[1][q] + rs2[2][q]) * (1.f / 192.f) - mean * mean;
    float rstd = rsqrtf(var + 1e-5f);
    float t = (v[q] - mean) * rstd * g + be;
    float ge = 0.5f * t * (1.f + erff(t * 0.70710678118f));
    su[q][tid] = ge * zs[(pos0 + q) * DI + tid];
  }
  __syncthreads();
  int o = tid % DM, half = tid / DM;
  const float* wr = Wo + o * DI + half * DM;
  float acc[PP];
#pragma unroll
  for (int q = 0; q < PP; q++) acc[q] = 0.f;
  for (int j = 0; j < DM; j++) {
    float w = wr[j];
#pragma unroll
    for (int q = 0; q < PP; q++) acc[q] += w * su[q][half * DM + j];
  }
  __shared__ float part[PP][DI];
#pragma unroll
  for (int q = 0; q < PP; q++) part[q][tid] = acc[q];
  __syncthreads();
  if (tid < DM) {
#pragma unroll
    for (int q = 0; q < PP; q++)
      out[(pos0 + q) * DM + tid] = part[q][tid] + part[q][tid + DM];
  }
}

extern "C" void kernel_launch(void* const* d_in, const int* in_sizes, int n_in,
                              void* d_out, int out_size, void* d_ws, size_t ws_size,
                              hipStream_t stream) {
  const float* x       = (const float*)d_in[0];
  const float* Wi      = (const float*)d_in[1];
  const float* cw      = (const float*)d_in[2];
  const float* cb      = (const float*)d_in[3];
  const float* Wp      = (const float*)d_in[4];
  const float* Ds      = (const float*)d_in[5];
  const float* A_logs  = (const float*)d_in[6];
  const float* dt_bias = (const float*)d_in[7];
  const float* ln_g    = (const float*)d_in[8];
  const float* ln_b    = (const float*)d_in[9];
  const float* Wo      = (const float*)d_in[10];
  float* out = (float*)d_out;

  float* ws = (float*)d_ws;
  float* xi    = ws;                       // NPOS*DI
  float* zs    = xi + (size_t)NPOS * DI;
  float* xc    = zs + (size_t)NPOS * DI;
  float* dtb   = xc + (size_t)NPOS * DI;   // NPOS*KD*RK
  float* dAb   = dtb + (size_t)NPOS * KD * RK;
  float* Bsb   = dAb + (size_t)NPOS * KD * RK;   // NPOS*KD*NS
  float* Csb   = Bsb + (size_t)NPOS * KD * NS;
  float* ybuf  = Csb + (size_t)NPOS * KD * NS;   // NB*KD*LT*DI
  unsigned short* Send = (unsigned short*)(ybuf + (size_t)NB * KD * LT * DI); // SEQ*NC*ELEM bf16
  float* Pend  = (float*)(Send + (size_t)SEQ * NC * ELEM);  // SEQ*NC*RK
  float* WpbF  = Pend + (size_t)SEQ * NC * RK;              // NOP*DI bf16
  // xcb (bf16 conv copy) aliases Send: dead before scanA writes Send.
  unsigned short* xcb = (unsigned short*)Send;
  unsigned short* Wpb = (unsigned short*)WpbF;

  k_inproj<<<NPOS / 16, 384, 0, stream>>>(x, Wi, xi, zs);
  k_conv<<<(NPOS * DI + 255) / 256, 256, 0, stream>>>(xi, cw, cb, xc, xcb);
  k_wprep<<<(NOP * DI + 255) / 256, 256, 0, stream>>>(Wp, Wpb);
  k_xproj<<<NPOS / 32, 128, 0, stream>>>(xcb, Wpb, A_logs, dt_bias, dtb, dAb, Bsb, Csb);
  k_scanA<<<NB * KD * NC, 192, 0, stream>>>(xc, dtb, dAb, Bsb, Send, Pend);
  k_scanB<<<SEQ * (ELEM / 512), 256, 0, stream>>>((unsigned int*)Send, Pend);
  k_scanD<<<NB * KD * NC, 192, 0, stream>>>(xc, dtb, dAb, Bsb, Csb, Ds, Send, ybuf);
  k_out<<<NPOS / 4, 192, 0, stream>>>(ybuf, zs, ln_g, ln_b, Wo, out);
}

// Round 7
// 298.031 us; speedup vs baseline: 1.2277x; 1.1430x over previous
//
#include <hip/hip_runtime.h>

// VMamba mixer forward, MI355X. bf16-MFMA in_proj + x_proj; packed-fp32
// two-phase chunked selective scan with incremental position stepping.

constexpr int DM   = 96;     // D_MODEL
constexpr int DI   = 192;    // D_INNER
constexpr int RK   = 6;      // DT_RANK
constexpr int NS   = 32;     // D_STATE (== HEAD_D)
constexpr int KD   = 4;      // directions
constexpr int HW   = 56;
constexpr int LT   = 3136;   // L = 56*56
constexpr int NB   = 8;      // batch
constexpr int NPOS = NB * LT;   // 25088
constexpr int NC   = 64;     // chunks per sequence
constexpr int CH   = 49;     // chunk length (64*49 = 3136)
constexpr int SEQ = NB * KD; // 32 sequences
constexpr int ELEM = RK * NS * NS;  // 6144 state elements per sequence
constexpr int NO   = 280;    // x_proj outputs (4*70)
constexpr int NOP  = 288;    // padded to 18 MFMA n-tiles
constexpr int NI   = 384;    // in_proj outputs (2*DI)

typedef __attribute__((ext_vector_type(8))) __bf16 bf16x8;
typedef __attribute__((ext_vector_type(4))) float f32x4;
typedef __attribute__((ext_vector_type(2))) float f32x2;

__device__ __forceinline__ float siluf(float x) { return x / (1.f + __expf(-x)); }

__device__ __forceinline__ unsigned short f2bf(float f) {  // RNE, finite inputs
  unsigned int u = __float_as_uint(f);
  u = (u + 0x7fffu + ((u >> 16) & 1u)) >> 16;
  return (unsigned short)u;
}
__device__ __forceinline__ float bf2f(unsigned short h) {
  return __uint_as_float(((unsigned int)h) << 16);
}
__device__ __forceinline__ unsigned int pack2(float a, float b) {
  return (unsigned int)f2bf(a) | ((unsigned int)f2bf(b) << 16);
}

// sequence index l of direction k  ->  spatial position p (row-major h*56+w)
__device__ __forceinline__ int seq2pos(int k, int l) {
  int m = (k & 2) ? (LT - 1 - l) : l;
  return (k & 1) ? ((m % HW) * HW + m / HW) : m;
}

// Incremental position walker: uniform per-step update, no div/mod.
struct PosWalk {
  int p, cnt, wlim, winc, wstep, wadj, wrst;
  __device__ __forceinline__ void init(int k, int l0) {
    p = seq2pos(k, l0);
    if (k == 0)      { cnt = 0;  wlim = -9; winc = 0;  wstep = 1;   wadj = 0;     wrst = 0;  }
    else if (k == 1) { cnt = l0 % HW; wlim = HW - 1; winc = 1; wstep = HW; wadj = -(LT - HW - 1); wrst = 0; }
    else if (k == 2) { cnt = 0;  wlim = -9; winc = 0;  wstep = -1;  wadj = 0;     wrst = 0;  }
    else             { cnt = (LT - 1 - l0) % HW; wlim = 0; winc = -1; wstep = -HW; wadj = LT - HW - 1; wrst = HW - 1; }
  }
  __device__ __forceinline__ void next() {
    bool wrap = (cnt == wlim);
    p += wrap ? wadj : wstep;
    cnt = wrap ? wrst : cnt + winc;
  }
};

// ---------------- Kernel 0a: Wi -> bf16 ----------------
__global__ __launch_bounds__(256) void k_wiprep(const float* __restrict__ Wi,
                                                unsigned short* __restrict__ Wib) {
  int t = blockIdx.x * 256 + threadIdx.x;
  if (t >= NI * DM) return;
  Wib[t] = f2bf(Wi[t]);
}

// ---------------- Kernel 0b: Wp -> bf16, padded to 288 rows ----------------
__global__ __launch_bounds__(256) void k_wprep(const float* __restrict__ Wp,
                                               unsigned short* __restrict__ Wpb) {
  int t = blockIdx.x * 256 + threadIdx.x;
  if (t >= NOP * DI) return;
  int o = t / DI;
  Wpb[t] = (o < NO) ? f2bf(Wp[t]) : (unsigned short)0;
}

// ---------------- Kernel 1: in_proj via bf16 MFMA + split + silu(z) ----------
// Wave = 16 positions; 24 n-tiles cover 384 outputs; K=96 in 3 steps.
__global__ __launch_bounds__(256) void k_inproj(const float* __restrict__ x,
                                                const unsigned short* __restrict__ Wib,
                                                float* __restrict__ xi,
                                                float* __restrict__ zs) {
  int wid = threadIdx.x >> 6;
  int lane = threadIdx.x & 63;
  int pos0 = blockIdx.x * 64 + wid * 16;
  int lrow = lane & 15;   // A: position-in-tile, B: output-in-tile
  int lgrp = lane >> 4;   // k-group (8 elements each)
  // A fragments: convert fp32 x -> bf16 in-register
  bf16x8 a[3];
  const float* arow = x + (size_t)(pos0 + lrow) * DM + lgrp * 8;
#pragma unroll
  for (int ks = 0; ks < 3; ks++) {
    f32x4 v0 = *reinterpret_cast<const f32x4*>(arow + ks * 32);
    f32x4 v1 = *reinterpret_cast<const f32x4*>(arow + ks * 32 + 4);
    union { unsigned short us[8]; bf16x8 v; } tmp;
#pragma unroll
    for (int j = 0; j < 4; j++) { tmp.us[j] = f2bf(v0[j]); tmp.us[4 + j] = f2bf(v1[j]); }
    a[ks] = tmp.v;
  }
  f32x4 acc[24];
#pragma unroll
  for (int t = 0; t < 24; t++) acc[t] = (f32x4){0.f, 0.f, 0.f, 0.f};
  const unsigned short* brow = Wib + (size_t)lrow * DM + lgrp * 8;
#pragma unroll
  for (int ks = 0; ks < 3; ks++) {
#pragma unroll
    for (int ot = 0; ot < 24; ot++) {
      bf16x8 bf = *reinterpret_cast<const bf16x8*>(brow + (size_t)ot * 16 * DM + ks * 32);
      acc[ot] = __builtin_amdgcn_mfma_f32_16x16x32_bf16(a[ks], bf, acc[ot], 0, 0, 0);
    }
  }
  // epilogue: col=lane&15 (output o), row=(lane>>4)*4+reg (position)
#pragma unroll
  for (int ot = 0; ot < 24; ot++) {
    int o = ot * 16 + lrow;
#pragma unroll
    for (int r = 0; r < 4; r++) {
      int pos = pos0 + lgrp * 4 + r;
      float v = acc[ot][r];
      if (o < DI) xi[(size_t)pos * DI + o] = v;
      else        zs[(size_t)pos * DI + (o - DI)] = siluf(v);
    }
  }
}

// ---------------- Kernel 2: depthwise 3x3 conv + bias + silu (+bf16 copy) ----
__global__ void k_conv(const float* __restrict__ xi, const float* __restrict__ cw,
                       const float* __restrict__ cb, float* __restrict__ xc,
                       unsigned short* __restrict__ xcb) {
  int t = blockIdx.x * 256 + threadIdx.x;
  if (t >= NPOS * DI) return;
  int c = t % DI;
  int pos = t / DI;
  int p = pos % LT, b = pos / LT;
  int h = p / HW, w = p % HW;
  float acc = cb[c];
#pragma unroll
  for (int dh = 0; dh < 3; dh++) {
    int hh = h + dh - 1;
    if (hh < 0 || hh >= HW) continue;
#pragma unroll
    for (int dw = 0; dw < 3; dw++) {
      int ww = w + dw - 1;
      if (ww < 0 || ww >= HW) continue;
      acc += cw[(dh * 3 + dw) * DI + c] * xi[(b * LT + hh * HW + ww) * DI + c];
    }
  }
  float v = siluf(acc);
  xc[t] = v;
  xcb[t] = f2bf(v);
}

// ---------------- Kernel 3: x_proj via bf16 MFMA + softplus/exp ----------------
__global__ __launch_bounds__(128) void k_xproj(const unsigned short* __restrict__ xcb,
                                               const unsigned short* __restrict__ Wpb,
                                               const float* __restrict__ A_logs,
                                               const float* __restrict__ dt_bias,
                                               float* __restrict__ dtb,
                                               float* __restrict__ dAb,
                                               float* __restrict__ Bsb,
                                               float* __restrict__ Csb) {
  int wid = threadIdx.x >> 6;
  int lane = threadIdx.x & 63;
  int pos0 = blockIdx.x * 32 + wid * 16;
  int lrow = lane & 15;   // A: position-in-tile, B: output-in-tile
  int lgrp = lane >> 4;   // k-group (8 bf16 each)
  bf16x8 a[6];
  const unsigned short* arow = xcb + (size_t)(pos0 + lrow) * DI + lgrp * 8;
#pragma unroll
  for (int ks = 0; ks < 6; ks++)
    a[ks] = *reinterpret_cast<const bf16x8*>(arow + ks * 32);
  f32x4 acc[18];
#pragma unroll
  for (int t = 0; t < 18; t++) acc[t] = (f32x4){0.f, 0.f, 0.f, 0.f};
  const unsigned short* brow = Wpb + (size_t)lrow * DI + lgrp * 8;
#pragma unroll
  for (int ks = 0; ks < 6; ks++) {
#pragma unroll
    for (int ot = 0; ot < 18; ot++) {
      bf16x8 bf = *reinterpret_cast<const bf16x8*>(brow + (size_t)ot * 16 * DI + ks * 32);
      acc[ot] = __builtin_amdgcn_mfma_f32_16x16x32_bf16(a[ks], bf, acc[ot], 0, 0, 0);
    }
  }
#pragma unroll
  for (int ot = 0; ot < 18; ot++) {
    int o = ot * 16 + lrow;
    if (o >= NO) continue;
    int k = o / 70, c = o % 70;
#pragma unroll
    for (int r = 0; r < 4; r++) {
      int pos = pos0 + lgrp * 4 + r;
      float v = acc[ot][r];
      int base = pos * KD + k;
      if (c < RK) {
        float bias = dt_bias[k * RK + c];
        float Av = -__expf(A_logs[k * RK + c]);
        float s = v + bias;
        float dtv = (s > 20.f) ? s : log1pf(__expf(s));
        dtb[base * RK + c] = dtv;
        dAb[base * RK + c] = __expf(dtv * Av);
      } else if (c < RK + NS) {
        Bsb[base * NS + (c - RK)] = v;
      } else {
        Csb[base * NS + (c - RK - NS)] = v;
      }
    }
  }
}

// ---------------- Kernel 4: states-only local scan (packed fp32) ----------------
__global__ __launch_bounds__(192) void k_scanA(const float* __restrict__ xc,
                                               const float* __restrict__ dtb,
                                               const float* __restrict__ dAb,
                                               const float* __restrict__ Bsb,
                                               unsigned short* __restrict__ Send,
                                               float* __restrict__ Pend) {
  int bi = blockIdx.x;
  int chunk = bi % NC;
  int k = (bi / NC) & 3;
  int b = bi / (NC * KD);
  int seq = b * KD + k;
  int tid = threadIdx.x;
  int r = tid >> 5, d = tid & 31;
  f32x2 S2[16];
#pragma unroll
  for (int i = 0; i < 16; i++) S2[i] = (f32x2){0.f, 0.f};
  float cum = 1.f;
  PosWalk pw; pw.init(k, chunk * CH);
  const float* xp = xc + (size_t)b * LT * DI + tid;
  size_t cb0 = (size_t)b * LT * KD + k;
  for (int l = 0; l < CH; l++) {
    size_t base = cb0 + (size_t)pw.p * KD;      // block-uniform
    const f32x4* Bp = reinterpret_cast<const f32x4*>(Bsb + base * NS);
    f32x4 bv[8];
#pragma unroll
    for (int i = 0; i < 8; i++) bv[i] = Bp[i];
    float dAr = dAb[base * RK + r];
    float dtr = dtb[base * RK + r];
    float xv = xp[(size_t)pw.p * DI];
    float xdt = xv * dtr;
    f32x2 dA2 = {dAr, dAr}, xd2 = {xdt, xdt};
#pragma unroll
    for (int i = 0; i < 8; i++) {
      f32x2 bl = __builtin_shufflevector(bv[i], bv[i], 0, 1);
      f32x2 bh = __builtin_shufflevector(bv[i], bv[i], 2, 3);
      S2[2 * i]     = S2[2 * i] * dA2 + xd2 * bl;
      S2[2 * i + 1] = S2[2 * i + 1] * dA2 + xd2 * bh;
    }
    cum *= dAr;
    pw.next();
  }
  unsigned int* dst = (unsigned int*)(Send + (size_t)(seq * NC + chunk) * ELEM + tid * NS);
#pragma unroll
  for (int i = 0; i < 16; i++) dst[i] = pack2(S2[i][0], S2[i][1]);
  if (d == 0) Pend[(seq * NC + chunk) * RK + r] = cum;
}

// ---------------- Kernel 5: chunk-state combine (bf16 in-place excl. prefix) ----
__global__ __launch_bounds__(256) void k_scanB(unsigned int* __restrict__ Send32,
                                               const float* __restrict__ Pend) {
  const int EU = ELEM / 2;           // 3072 uints per (seq,chunk)
  int bi = blockIdx.x;               // 32 seqs * 12 uint-tiles
  int seq = bi / (EU / 256);
  int u = (bi % (EU / 256)) * 256 + threadIdx.x;
  int r = u >> 9;                    // element e = 2u, r = e>>10
  float run0 = 0.f, run1 = 0.f;
  for (int c = 0; c < NC; c++) {
    size_t idx = (size_t)(seq * NC + c) * EU + u;
    unsigned int v = Send32[idx];
    float t0 = bf2f((unsigned short)(v & 0xffff));
    float t1 = bf2f((unsigned short)(v >> 16));
    Send32[idx] = pack2(run0, run1);
    float pe = Pend[(seq * NC + c) * RK + r];
    run0 = run0 * pe + t0;
    run1 = run1 * pe + t1;
  }
}

// ---------------- Kernel 6: full scan recompute seeded with Sinit (packed) ----
__global__ __launch_bounds__(192) void k_scanD(const float* __restrict__ xc,
                                               const float* __restrict__ dtb,
                                               const float* __restrict__ dAb,
                                               const float* __restrict__ Bsb,
                                               const float* __restrict__ Csb,
                                               const float* __restrict__ Ds,
                                               const unsigned short* __restrict__ Sinit,
                                               float* __restrict__ ybuf) {
  int bi = blockIdx.x;
  int chunk = bi % NC;
  int k = (bi / NC) & 3;
  int b = bi / (NC * KD);
  int seq = b * KD + k;
  int tid = threadIdx.x;
  int r = tid >> 5, d = tid & 31;
  f32x2 S2[16];
  const unsigned int* sp = (const unsigned int*)(Sinit + (size_t)(seq * NC + chunk) * ELEM + tid * NS);
#pragma unroll
  for (int i = 0; i < 16; i++) {
    unsigned int v = sp[i];
    S2[i] = (f32x2){bf2f((unsigned short)(v & 0xffff)), bf2f((unsigned short)(v >> 16))};
  }
  float Dsv = Ds[(k * RK + r) * NS + d];
  PosWalk pw; pw.init(k, chunk * CH);
  const float* xp = xc + (size_t)b * LT * DI + tid;
  float* yb = ybuf + (size_t)seq * LT * DI + tid;
  size_t cb0 = (size_t)b * LT * KD + k;
  for (int l = 0; l < CH; l++) {
    size_t base = cb0 + (size_t)pw.p * KD;      // block-uniform
    const f32x4* Bp = reinterpret_cast<const f32x4*>(Bsb + base * NS);
    const f32x4* Cp = reinterpret_cast<const f32x4*>(Csb + base * NS);
    f32x4 bv[8], cv[8];
#pragma unroll
    for (int i = 0; i < 8; i++) { bv[i] = Bp[i]; cv[i] = Cp[i]; }
    float dAr = dAb[base * RK + r];
    float dtr = dtb[base * RK + r];
    float xv = xp[(size_t)pw.p * DI];
    float xdt = xv * dtr;
    f32x2 dA2 = {dAr, dAr}, xd2 = {xdt, xdt};
    f32x2 y2 = {0.f, 0.f};
#pragma unroll
    for (int i = 0; i < 8; i++) {
      f32x2 bl = __builtin_shufflevector(bv[i], bv[i], 0, 1);
      f32x2 bh = __builtin_shufflevector(bv[i], bv[i], 2, 3);
      f32x2 cl = __builtin_shufflevector(cv[i], cv[i], 0, 1);
      f32x2 ch = __builtin_shufflevector(cv[i], cv[i], 2, 3);
      S2[2 * i]     = S2[2 * i] * dA2 + xd2 * bl;
      y2 += S2[2 * i] * cl;
      S2[2 * i + 1] = S2[2 * i + 1] * dA2 + xd2 * bh;
      y2 += S2[2 * i + 1] * ch;
    }
    yb[(size_t)pw.p * DI] = y2[0] + y2[1] + xv * Dsv;
    pw.next();
  }
}

// ---------------- Kernel 7: merge + LN + gelu + *silu(z) + out_proj ----------------
__global__ __launch_bounds__(192) void k_out(const float* __restrict__ ybuf,
                                             const float* __restrict__ zs,
                                             const float* __restrict__ ln_g,
                                             const float* __restrict__ ln_b,
                                             const float* __restrict__ Wo,
                                             float* __restrict__ out) {
  const int PP = 4;
  int pos0 = blockIdx.x * PP;
  int b = pos0 / LT, p0 = pos0 % LT;
  int tid = threadIdx.x;  // 0..191 = channel
  float v[PP], s1[PP], s2[PP];
#pragma unroll
  for (int q = 0; q < PP; q++) {
    float acc = 0.f;
#pragma unroll
    for (int k = 0; k < KD; k++) acc += ybuf[((size_t)(b * KD + k) * LT + p0 + q) * DI + tid];
    v[q] = acc; s1[q] = acc; s2[q] = acc * acc;
  }
#pragma unroll
  for (int off = 32; off; off >>= 1) {
#pragma unroll
    for (int q = 0; q < PP; q++) {
      s1[q] += __shfl_down(s1[q], off, 64);
      s2[q] += __shfl_down(s2[q], off, 64);
    }
  }
  __shared__ float rs1[3][PP], rs2[3][PP];
  int wave = tid >> 6, lane = tid & 63;
  if (lane == 0) {
#pragma unroll
    for (int q = 0; q < PP; q++) { rs1[wave][q] = s1[q]; rs2[wave][q] = s2[q]; }
  }
  __syncthreads();
  __shared__ float su[PP][DI];
  float g = ln_g[tid], be = ln_b[tid];
#pragma unroll
  for (int q = 0; q < PP; q++) {
    float mean = (rs1[0][q] + rs1[1][q] + rs1[2][q]) * (1.f / 192.f);
    float var = (rs2[0][q] + rs2[1][q] + rs2[2][q]) * (1.f / 192.f) - mean * mean;
    float rstd = rsqrtf(var + 1e-5f);
    float t = (v[q] - mean) * rstd * g + be;
    float ge = 0.5f * t * (1.f + erff(t * 0.70710678118f));
    su[q][tid] = ge * zs[(pos0 + q) * DI + tid];
  }
  __syncthreads();
  int o = tid % DM, half = tid / DM;
  const float* wr = Wo + o * DI + half * DM;
  float acc[PP];
#pragma unroll
  for (int q = 0; q < PP; q++) acc[q] = 0.f;
  for (int j = 0; j < DM; j++) {
    float w = wr[j];
#pragma unroll
    for (int q = 0; q < PP; q++) acc[q] += w * su[q][half * DM + j];
  }
  __shared__ float part[PP][DI];
#pragma unroll
  for (int q = 0; q < PP; q++) part[q][tid] = acc[q];
  __syncthreads();
  if (tid < DM) {
#pragma unroll
    for (int q = 0; q < PP; q++)
      out[(pos0 + q) * DM + tid] = part[q][tid] + part[q][tid + DM];
  }
}

extern "C" void kernel_launch(void* const* d_in, const int* in_sizes, int n_in,
                              void* d_out, int out_size, void* d_ws, size_t ws_size,
                              hipStream_t stream) {
  const float* x       = (const float*)d_in[0];
  const float* Wi      = (const float*)d_in[1];
  const float* cw      = (const float*)d_in[2];
  const float* cb      = (const float*)d_in[3];
  const float* Wp      = (const float*)d_in[4];
  const float* Ds      = (const float*)d_in[5];
  const float* A_logs  = (const float*)d_in[6];
  const float* dt_bias = (const float*)d_in[7];
  const float* ln_g    = (const float*)d_in[8];
  const float* ln_b    = (const float*)d_in[9];
  const float* Wo      = (const float*)d_in[10];
  float* out = (float*)d_out;

  float* ws = (float*)d_ws;
  float* xi    = ws;                       // NPOS*DI
  float* zs    = xi + (size_t)NPOS * DI;
  float* xc    = zs + (size_t)NPOS * DI;
  float* dtb   = xc + (size_t)NPOS * DI;   // NPOS*KD*RK
  float* dAb   = dtb + (size_t)NPOS * KD * RK;
  float* Bsb   = dAb + (size_t)NPOS * KD * RK;   // NPOS*KD*NS
  float* Csb   = Bsb + (size_t)NPOS * KD * NS;
  float* ybuf  = Csb + (size_t)NPOS * KD * NS;   // NB*KD*LT*DI
  unsigned short* Send = (unsigned short*)(ybuf + (size_t)NB * KD * LT * DI); // SEQ*NC*ELEM bf16
  float* Pend  = (float*)(Send + (size_t)SEQ * NC * ELEM);  // SEQ*NC*RK
  float* WpbF  = Pend + (size_t)SEQ * NC * RK;              // NOP*DI bf16
  float* WibF  = WpbF + (size_t)NOP * DI / 2;               // NI*DM bf16
  // xcb (bf16 conv copy) aliases Send: dead before scanA writes Send.
  unsigned short* xcb = (unsigned short*)Send;
  unsigned short* Wpb = (unsigned short*)WpbF;
  unsigned short* Wib = (unsigned short*)WibF;

  k_wiprep<<<(NI * DM + 255) / 256, 256, 0, stream>>>(Wi, Wib);
  k_wprep<<<(NOP * DI + 255) / 256, 256, 0, stream>>>(Wp, Wpb);
  k_inproj<<<NPOS / 64, 256, 0, stream>>>(x, Wib, xi, zs);
  k_conv<<<(NPOS * DI + 255) / 256, 256, 0, stream>>>(xi, cw, cb, xc, xcb);
  k_xproj<<<NPOS / 32, 128, 0, stream>>>(xcb, Wpb, A_logs, dt_bias, dtb, dAb, Bsb, Csb);
  k_scanA<<<NB * KD * NC, 192, 0, stream>>>(xc, dtb, dAb, Bsb, Send, Pend);
  k_scanB<<<SEQ * (ELEM / 512), 256, 0, stream>>>((unsigned int*)Send, Pend);
  k_scanD<<<NB * KD * NC, 192, 0, stream>>>(xc, dtb, dAb, Bsb, Csb, Ds, Send, ybuf);
  k_out<<<NPOS / 4, 192, 0, stream>>>(ybuf, zs, ln_g, ln_b, Wo, out);
}

// Round 8
// 268.425 us; speedup vs baseline: 1.3631x; 1.1103x over previous
//
#include <hip/hip_runtime.h>

// VMamba mixer forward, MI355X. bf16-MFMA in_proj + x_proj; packed-fp32
// two-phase chunked selective scan; coalesced (transposed-Wo) output GEMM.

constexpr int DM   = 96;     // D_MODEL
constexpr int DI   = 192;    // D_INNER
constexpr int RK   = 6;      // DT_RANK
constexpr int NS   = 32;     // D_STATE (== HEAD_D)
constexpr int KD   = 4;      // directions
constexpr int HW   = 56;
constexpr int LT   = 3136;   // L = 56*56
constexpr int NB   = 8;      // batch
constexpr int NPOS = NB * LT;   // 25088
constexpr int NC   = 64;     // chunks per sequence
constexpr int CH   = 49;     // chunk length (64*49 = 3136)
constexpr int SEQ = NB * KD; // 32 sequences
constexpr int ELEM = RK * NS * NS;  // 6144 state elements per sequence
constexpr int NO   = 280;    // x_proj outputs (4*70)
constexpr int NOP  = 288;    // padded to 18 MFMA n-tiles
constexpr int NI   = 384;    // in_proj outputs (2*DI)

typedef __attribute__((ext_vector_type(8))) __bf16 bf16x8;
typedef __attribute__((ext_vector_type(4))) float f32x4;
typedef __attribute__((ext_vector_type(2))) float f32x2;

__device__ __forceinline__ float siluf(float x) { return x / (1.f + __expf(-x)); }

__device__ __forceinline__ unsigned short f2bf(float f) {  // RNE, finite inputs
  unsigned int u = __float_as_uint(f);
  u = (u + 0x7fffu + ((u >> 16) & 1u)) >> 16;
  return (unsigned short)u;
}
__device__ __forceinline__ float bf2f(unsigned short h) {
  return __uint_as_float(((unsigned int)h) << 16);
}
__device__ __forceinline__ unsigned int pack2(float a, float b) {
  return (unsigned int)f2bf(a) | ((unsigned int)f2bf(b) << 16);
}

// sequence index l of direction k  ->  spatial position p (row-major h*56+w)
__device__ __forceinline__ int seq2pos(int k, int l) {
  int m = (k & 2) ? (LT - 1 - l) : l;
  return (k & 1) ? ((m % HW) * HW + m / HW) : m;
}

// Incremental position walker: uniform per-step update, no div/mod.
struct PosWalk {
  int p, cnt, wlim, winc, wstep, wadj, wrst;
  __device__ __forceinline__ void init(int k, int l0) {
    p = seq2pos(k, l0);
    if (k == 0)      { cnt = 0;  wlim = -9; winc = 0;  wstep = 1;   wadj = 0;     wrst = 0;  }
    else if (k == 1) { cnt = l0 % HW; wlim = HW - 1; winc = 1; wstep = HW; wadj = -(LT - HW - 1); wrst = 0; }
    else if (k == 2) { cnt = 0;  wlim = -9; winc = 0;  wstep = -1;  wadj = 0;     wrst = 0;  }
    else             { cnt = (LT - 1 - l0) % HW; wlim = 0; winc = -1; wstep = -HW; wadj = LT - HW - 1; wrst = HW - 1; }
  }
  __device__ __forceinline__ void next() {
    bool wrap = (cnt == wlim);
    p += wrap ? wadj : wstep;
    cnt = wrap ? wrst : cnt + winc;
  }
};

// ---------------- Kernel 0a: Wi -> bf16 ----------------
__global__ __launch_bounds__(256) void k_wiprep(const float* __restrict__ Wi,
                                                unsigned short* __restrict__ Wib) {
  int t = blockIdx.x * 256 + threadIdx.x;
  if (t >= NI * DM) return;
  Wib[t] = f2bf(Wi[t]);
}

// ---------------- Kernel 0b: Wp -> bf16, padded to 288 rows ----------------
__global__ __launch_bounds__(256) void k_wprep(const float* __restrict__ Wp,
                                               unsigned short* __restrict__ Wpb) {
  int t = blockIdx.x * 256 + threadIdx.x;
  if (t >= NOP * DI) return;
  int o = t / DI;
  Wpb[t] = (o < NO) ? f2bf(Wp[t]) : (unsigned short)0;
}

// ---------------- Kernel 0c: Wo -> transposed fp32 Wot[DI][DM] ----------------
__global__ __launch_bounds__(256) void k_woprep(const float* __restrict__ Wo,
                                                float* __restrict__ Wot) {
  int t = blockIdx.x * 256 + threadIdx.x;
  if (t >= DM * DI) return;
  int o = t / DI, j = t % DI;
  Wot[j * DM + o] = Wo[t];
}

// ---------------- Kernel 1: in_proj via bf16 MFMA + split + silu(z) ----------
__global__ __launch_bounds__(256) void k_inproj(const float* __restrict__ x,
                                                const unsigned short* __restrict__ Wib,
                                                float* __restrict__ xi,
                                                float* __restrict__ zs) {
  int wid = threadIdx.x >> 6;
  int lane = threadIdx.x & 63;
  int pos0 = blockIdx.x * 64 + wid * 16;
  int lrow = lane & 15;   // A: position-in-tile, B: output-in-tile
  int lgrp = lane >> 4;   // k-group (8 elements each)
  bf16x8 a[3];
  const float* arow = x + (size_t)(pos0 + lrow) * DM + lgrp * 8;
#pragma unroll
  for (int ks = 0; ks < 3; ks++) {
    f32x4 v0 = *reinterpret_cast<const f32x4*>(arow + ks * 32);
    f32x4 v1 = *reinterpret_cast<const f32x4*>(arow + ks * 32 + 4);
    union { unsigned short us[8]; bf16x8 v; } tmp;
#pragma unroll
    for (int j = 0; j < 4; j++) { tmp.us[j] = f2bf(v0[j]); tmp.us[4 + j] = f2bf(v1[j]); }
    a[ks] = tmp.v;
  }
  f32x4 acc[24];
#pragma unroll
  for (int t = 0; t < 24; t++) acc[t] = (f32x4){0.f, 0.f, 0.f, 0.f};
  const unsigned short* brow = Wib + (size_t)lrow * DM + lgrp * 8;
#pragma unroll
  for (int ks = 0; ks < 3; ks++) {
#pragma unroll
    for (int ot = 0; ot < 24; ot++) {
      bf16x8 bf = *reinterpret_cast<const bf16x8*>(brow + (size_t)ot * 16 * DM + ks * 32);
      acc[ot] = __builtin_amdgcn_mfma_f32_16x16x32_bf16(a[ks], bf, acc[ot], 0, 0, 0);
    }
  }
#pragma unroll
  for (int ot = 0; ot < 24; ot++) {
    int o = ot * 16 + lrow;
#pragma unroll
    for (int r = 0; r < 4; r++) {
      int pos = pos0 + lgrp * 4 + r;
      float v = acc[ot][r];
      if (o < DI) xi[(size_t)pos * DI + o] = v;
      else        zs[(size_t)pos * DI + (o - DI)] = siluf(v);
    }
  }
}

// ---------------- Kernel 2: depthwise 3x3 conv + bias + silu (+bf16 copy) ----
__global__ void k_conv(const float* __restrict__ xi, const float* __restrict__ cw,
                       const float* __restrict__ cb, float* __restrict__ xc,
                       unsigned short* __restrict__ xcb) {
  int t = blockIdx.x * 256 + threadIdx.x;
  if (t >= NPOS * DI) return;
  int c = t % DI;
  int pos = t / DI;
  int p = pos % LT, b = pos / LT;
  int h = p / HW, w = p % HW;
  float acc = cb[c];
#pragma unroll
  for (int dh = 0; dh < 3; dh++) {
    int hh = h + dh - 1;
    if (hh < 0 || hh >= HW) continue;
#pragma unroll
    for (int dw = 0; dw < 3; dw++) {
      int ww = w + dw - 1;
      if (ww < 0 || ww >= HW) continue;
      acc += cw[(dh * 3 + dw) * DI + c] * xi[(b * LT + hh * HW + ww) * DI + c];
    }
  }
  float v = siluf(acc);
  xc[t] = v;
  xcb[t] = f2bf(v);
}

// ---------------- Kernel 3: x_proj via bf16 MFMA + softplus/exp ----------------
__global__ __launch_bounds__(128) void k_xproj(const unsigned short* __restrict__ xcb,
                                               const unsigned short* __restrict__ Wpb,
                                               const float* __restrict__ A_logs,
                                               const float* __restrict__ dt_bias,
                                               float* __restrict__ dtb,
                                               float* __restrict__ dAb,
                                               float* __restrict__ Bsb,
                                               float* __restrict__ Csb) {
  int wid = threadIdx.x >> 6;
  int lane = threadIdx.x & 63;
  int pos0 = blockIdx.x * 32 + wid * 16;
  int lrow = lane & 15;   // A: position-in-tile, B: output-in-tile
  int lgrp = lane >> 4;   // k-group (8 bf16 each)
  bf16x8 a[6];
  const unsigned short* arow = xcb + (size_t)(pos0 + lrow) * DI + lgrp * 8;
#pragma unroll
  for (int ks = 0; ks < 6; ks++)
    a[ks] = *reinterpret_cast<const bf16x8*>(arow + ks * 32);
  f32x4 acc[18];
#pragma unroll
  for (int t = 0; t < 18; t++) acc[t] = (f32x4){0.f, 0.f, 0.f, 0.f};
  const unsigned short* brow = Wpb + (size_t)lrow * DI + lgrp * 8;
#pragma unroll
  for (int ks = 0; ks < 6; ks++) {
#pragma unroll
    for (int ot = 0; ot < 18; ot++) {
      bf16x8 bf = *reinterpret_cast<const bf16x8*>(brow + (size_t)ot * 16 * DI + ks * 32);
      acc[ot] = __builtin_amdgcn_mfma_f32_16x16x32_bf16(a[ks], bf, acc[ot], 0, 0, 0);
    }
  }
#pragma unroll
  for (int ot = 0; ot < 18; ot++) {
    int o = ot * 16 + lrow;
    if (o >= NO) continue;
    int k = o / 70, c = o % 70;
#pragma unroll
    for (int r = 0; r < 4; r++) {
      int pos = pos0 + lgrp * 4 + r;
      float v = acc[ot][r];
      int base = pos * KD + k;
      if (c < RK) {
        float bias = dt_bias[k * RK + c];
        float Av = -__expf(A_logs[k * RK + c]);
        float s = v + bias;
        float dtv = (s > 20.f) ? s : log1pf(__expf(s));
        dtb[base * RK + c] = dtv;
        dAb[base * RK + c] = __expf(dtv * Av);
      } else if (c < RK + NS) {
        Bsb[base * NS + (c - RK)] = v;
      } else {
        Csb[base * NS + (c - RK - NS)] = v;
      }
    }
  }
}

// ---------------- Kernel 4: states-only local scan (packed fp32) ----------------
__global__ __launch_bounds__(192) void k_scanA(const float* __restrict__ xc,
                                               const float* __restrict__ dtb,
                                               const float* __restrict__ dAb,
                                               const float* __restrict__ Bsb,
                                               unsigned short* __restrict__ Send,
                                               float* __restrict__ Pend) {
  int bi = blockIdx.x;
  int chunk = bi % NC;
  int k = (bi / NC) & 3;
  int b = bi / (NC * KD);
  int seq = b * KD + k;
  int tid = threadIdx.x;
  int r = tid >> 5, d = tid & 31;
  f32x2 S2[16];
#pragma unroll
  for (int i = 0; i < 16; i++) S2[i] = (f32x2){0.f, 0.f};
  float cum = 1.f;
  PosWalk pw; pw.init(k, chunk * CH);
  const float* xp = xc + (size_t)b * LT * DI + tid;
  size_t cb0 = (size_t)b * LT * KD + k;
  for (int l = 0; l < CH; l++) {
    size_t base = cb0 + (size_t)pw.p * KD;      // block-uniform
    const f32x4* Bp = reinterpret_cast<const f32x4*>(Bsb + base * NS);
    f32x4 bv[8];
#pragma unroll
    for (int i = 0; i < 8; i++) bv[i] = Bp[i];
    float dAr = dAb[base * RK + r];
    float dtr = dtb[base * RK + r];
    float xv = xp[(size_t)pw.p * DI];
    float xdt = xv * dtr;
    f32x2 dA2 = {dAr, dAr}, xd2 = {xdt, xdt};
#pragma unroll
    for (int i = 0; i < 8; i++) {
      f32x2 bl = __builtin_shufflevector(bv[i], bv[i], 0, 1);
      f32x2 bh = __builtin_shufflevector(bv[i], bv[i], 2, 3);
      S2[2 * i]     = S2[2 * i] * dA2 + xd2 * bl;
      S2[2 * i + 1] = S2[2 * i + 1] * dA2 + xd2 * bh;
    }
    cum *= dAr;
    pw.next();
  }
  unsigned int* dst = (unsigned int*)(Send + (size_t)(seq * NC + chunk) * ELEM + tid * NS);
#pragma unroll
  for (int i = 0; i < 16; i++) dst[i] = pack2(S2[i][0], S2[i][1]);
  if (d == 0) Pend[(seq * NC + chunk) * RK + r] = cum;
}

// ---------------- Kernel 5: chunk-state combine (bf16 in-place excl. prefix) ----
__global__ __launch_bounds__(256) void k_scanB(unsigned int* __restrict__ Send32,
                                               const float* __restrict__ Pend) {
  const int EU = ELEM / 2;           // 3072 uints per (seq,chunk)
  int bi = blockIdx.x;               // 32 seqs * 12 uint-tiles
  int seq = bi / (EU / 256);
  int u = (bi % (EU / 256)) * 256 + threadIdx.x;
  int r = u >> 9;                    // element e = 2u, r = e>>10
  float run0 = 0.f, run1 = 0.f;
  for (int c = 0; c < NC; c++) {
    size_t idx = (size_t)(seq * NC + c) * EU + u;
    unsigned int v = Send32[idx];
    float t0 = bf2f((unsigned short)(v & 0xffff));
    float t1 = bf2f((unsigned short)(v >> 16));
    Send32[idx] = pack2(run0, run1);
    float pe = Pend[(seq * NC + c) * RK + r];
    run0 = run0 * pe + t0;
    run1 = run1 * pe + t1;
  }
}

// ---------------- Kernel 6: full scan recompute seeded with Sinit (packed) ----
__global__ __launch_bounds__(192) void k_scanD(const float* __restrict__ xc,
                                               const float* __restrict__ dtb,
                                               const float* __restrict__ dAb,
                                               const float* __restrict__ Bsb,
                                               const float* __restrict__ Csb,
                                               const float* __restrict__ Ds,
                                               const unsigned short* __restrict__ Sinit,
                                               float* __restrict__ ybuf) {
  int bi = blockIdx.x;
  int chunk = bi % NC;
  int k = (bi / NC) & 3;
  int b = bi / (NC * KD);
  int seq = b * KD + k;
  int tid = threadIdx.x;
  int r = tid >> 5, d = tid & 31;
  f32x2 S2[16];
  const unsigned int* sp = (const unsigned int*)(Sinit + (size_t)(seq * NC + chunk) * ELEM + tid * NS);
#pragma unroll
  for (int i = 0; i < 16; i++) {
    unsigned int v = sp[i];
    S2[i] = (f32x2){bf2f((unsigned short)(v & 0xffff)), bf2f((unsigned short)(v >> 16))};
  }
  float Dsv = Ds[(k * RK + r) * NS + d];
  PosWalk pw; pw.init(k, chunk * CH);
  const float* xp = xc + (size_t)b * LT * DI + tid;
  float* yb = ybuf + (size_t)seq * LT * DI + tid;
  size_t cb0 = (size_t)b * LT * KD + k;
  for (int l = 0; l < CH; l++) {
    size_t base = cb0 + (size_t)pw.p * KD;      // block-uniform
    const f32x4* Bp = reinterpret_cast<const f32x4*>(Bsb + base * NS);
    const f32x4* Cp = reinterpret_cast<const f32x4*>(Csb + base * NS);
    f32x4 bv[8], cv[8];
#pragma unroll
    for (int i = 0; i < 8; i++) { bv[i] = Bp[i]; cv[i] = Cp[i]; }
    float dAr = dAb[base * RK + r];
    float dtr = dtb[base * RK + r];
    float xv = xp[(size_t)pw.p * DI];
    float xdt = xv * dtr;
    f32x2 dA2 = {dAr, dAr}, xd2 = {xdt, xdt};
    f32x2 y2 = {0.f, 0.f};
#pragma unroll
    for (int i = 0; i < 8; i++) {
      f32x2 bl = __builtin_shufflevector(bv[i], bv[i], 0, 1);
      f32x2 bh = __builtin_shufflevector(bv[i], bv[i], 2, 3);
      f32x2 cl = __builtin_shufflevector(cv[i], cv[i], 0, 1);
      f32x2 ch = __builtin_shufflevector(cv[i], cv[i], 2, 3);
      S2[2 * i]     = S2[2 * i] * dA2 + xd2 * bl;
      y2 += S2[2 * i] * cl;
      S2[2 * i + 1] = S2[2 * i + 1] * dA2 + xd2 * bh;
      y2 += S2[2 * i + 1] * ch;
    }
    yb[(size_t)pw.p * DI] = y2[0] + y2[1] + xv * Dsv;
    pw.next();
  }
}

// ---------------- Kernel 7: merge + LN + gelu + *silu(z) + out_proj ----------------
// Wot is the transposed Wo: Wot[j][o], so weight loads are lane-coalesced.
__global__ __launch_bounds__(192) void k_out(const float* __restrict__ ybuf,
                                             const float* __restrict__ zs,
                                             const float* __restrict__ ln_g,
                                             const float* __restrict__ ln_b,
                                             const float* __restrict__ Wot,
                                             float* __restrict__ out) {
  const int PP = 4;
  int pos0 = blockIdx.x * PP;
  int b = pos0 / LT, p0 = pos0 % LT;
  int tid = threadIdx.x;  // 0..191 = channel
  float v[PP], s1[PP], s2[PP];
#pragma unroll
  for (int q = 0; q < PP; q++) {
    float acc = 0.f;
#pragma unroll
    for (int k = 0; k < KD; k++) acc += ybuf[((size_t)(b * KD + k) * LT + p0 + q) * DI + tid];
    v[q] = acc; s1[q] = acc; s2[q] = acc * acc;
  }
#pragma unroll
  for (int off = 32; off; off >>= 1) {
#pragma unroll
    for (int q = 0; q < PP; q++) {
      s1[q] += __shfl_down(s1[q], off, 64);
      s2[q] += __shfl_down(s2[q], off, 64);
    }
  }
  __shared__ float rs1[3][PP], rs2[3][PP];
  int wave = tid >> 6, lane = tid & 63;
  if (lane == 0) {
#pragma unroll
    for (int q = 0; q < PP; q++) { rs1[wave][q] = s1[q]; rs2[wave][q] = s2[q]; }
  }
  __syncthreads();
  __shared__ float su[PP][DI];
  float g = ln_g[tid], be = ln_b[tid];
#pragma unroll
  for (int q = 0; q < PP; q++) {
    float mean = (rs1[0][q] + rs1[1][q] + rs1[2][q]) * (1.f / 192.f);
    float var = (rs2[0][q] + rs2[1][q] + rs2[2][q]) * (1.f / 192.f) - mean * mean;
    float rstd = rsqrtf(var + 1e-5f);
    float t = (v[q] - mean) * rstd * g + be;
    float ge = 0.5f * t * (1.f + erff(t * 0.70710678118f));
    su[q][tid] = ge * zs[(pos0 + q) * DI + tid];
  }
  __syncthreads();
  int o = tid % DM, half = tid / DM;  // 2 threads per output column
  const float* wcol = Wot + (size_t)half * DM * DM + o;  // Wot[(half*DM+j)*DM + o]
  float acc[PP];
#pragma unroll
  for (int q = 0; q < PP; q++) acc[q] = 0.f;
  for (int j = 0; j < DM; j++) {
    float w = wcol[(size_t)j * DM];   // lane-coalesced: o consecutive
#pragma unroll
    for (int q = 0; q < PP; q++) acc[q] += w * su[q][half * DM + j];
  }
  __shared__ float part[PP][DI];
#pragma unroll
  for (int q = 0; q < PP; q++) part[q][tid] = acc[q];
  __syncthreads();
  if (tid < DM) {
#pragma unroll
    for (int q = 0; q < PP; q++)
      out[(pos0 + q) * DM + tid] = part[q][tid] + part[q][tid + DM];
  }
}

extern "C" void kernel_launch(void* const* d_in, const int* in_sizes, int n_in,
                              void* d_out, int out_size, void* d_ws, size_t ws_size,
                              hipStream_t stream) {
  const float* x       = (const float*)d_in[0];
  const float* Wi      = (const float*)d_in[1];
  const float* cw      = (const float*)d_in[2];
  const float* cb      = (const float*)d_in[3];
  const float* Wp      = (const float*)d_in[4];
  const float* Ds      = (const float*)d_in[5];
  const float* A_logs  = (const float*)d_in[6];
  const float* dt_bias = (const float*)d_in[7];
  const float* ln_g    = (const float*)d_in[8];
  const float* ln_b    = (const float*)d_in[9];
  const float* Wo      = (const float*)d_in[10];
  float* out = (float*)d_out;

  float* ws = (float*)d_ws;
  float* xi    = ws;                       // NPOS*DI
  float* zs    = xi + (size_t)NPOS * DI;
  float* xc    = zs + (size_t)NPOS * DI;
  float* dtb   = xc + (size_t)NPOS * DI;   // NPOS*KD*RK
  float* dAb   = dtb + (size_t)NPOS * KD * RK;
  float* Bsb   = dAb + (size_t)NPOS * KD * RK;   // NPOS*KD*NS
  float* Csb   = Bsb + (size_t)NPOS * KD * NS;
  float* ybuf  = Csb + (size_t)NPOS * KD * NS;   // NB*KD*LT*DI
  unsigned short* Send = (unsigned short*)(ybuf + (size_t)NB * KD * LT * DI); // SEQ*NC*ELEM bf16
  float* Pend  = (float*)(Send + (size_t)SEQ * NC * ELEM);  // SEQ*NC*RK
  float* WpbF  = Pend + (size_t)SEQ * NC * RK;              // NOP*DI bf16
  float* WibF  = WpbF + (size_t)NOP * DI / 2;               // NI*DM bf16
  float* Wot   = WibF + (size_t)NI * DM / 2;                // DI*DM fp32
  // xcb (bf16 conv copy) aliases Send: dead before scanA writes Send.
  unsigned short* xcb = (unsigned short*)Send;
  unsigned short* Wpb = (unsigned short*)WpbF;
  unsigned short* Wib = (unsigned short*)WibF;

  k_wiprep<<<(NI * DM + 255) / 256, 256, 0, stream>>>(Wi, Wib);
  k_wprep<<<(NOP * DI + 255) / 256, 256, 0, stream>>>(Wp, Wpb);
  k_woprep<<<(DM * DI + 255) / 256, 256, 0, stream>>>(Wo, Wot);
  k_inproj<<<NPOS / 64, 256, 0, stream>>>(x, Wib, xi, zs);
  k_conv<<<(NPOS * DI + 255) / 256, 256, 0, stream>>>(xi, cw, cb, xc, xcb);
  k_xproj<<<NPOS / 32, 128, 0, stream>>>(xcb, Wpb, A_logs, dt_bias, dtb, dAb, Bsb, Csb);
  k_scanA<<<NB * KD * NC, 192, 0, stream>>>(xc, dtb, dAb, Bsb, Send, Pend);
  k_scanB<<<SEQ * (ELEM / 512), 256, 0, stream>>>((unsigned int*)Send, Pend);
  k_scanD<<<NB * KD * NC, 192, 0, stream>>>(xc, dtb, dAb, Bsb, Csb, Ds, Send, ybuf);
  k_out<<<NPOS / 4, 192, 0, stream>>>(ybuf, zs, ln_g, ln_b, Wot, out);
}

// Round 9
// 260.034 us; speedup vs baseline: 1.4070x; 1.0323x over previous
//
#include <hip/hip_runtime.h>

// VMamba mixer forward, MI355X. bf16-MFMA in_proj + x_proj; packed-fp32
// two-phase chunked selective scan on bf16 x; bf16 ybuf; transposed-Wo out GEMM.

constexpr int DM   = 96;     // D_MODEL
constexpr int DI   = 192;    // D_INNER
constexpr int RK   = 6;      // DT_RANK
constexpr int NS   = 32;     // D_STATE (== HEAD_D)
constexpr int KD   = 4;      // directions
constexpr int HW   = 56;
constexpr int LT   = 3136;   // L = 56*56
constexpr int NB   = 8;      // batch
constexpr int NPOS = NB * LT;   // 25088
constexpr int NC   = 64;     // chunks per sequence
constexpr int CH   = 49;     // chunk length (64*49 = 3136)
constexpr int SEQ = NB * KD; // 32 sequences
constexpr int ELEM = RK * NS * NS;  // 6144 state elements per sequence
constexpr int NO   = 280;    // x_proj outputs (4*70)
constexpr int NOP  = 288;    // padded to 18 MFMA n-tiles
constexpr int NI   = 384;    // in_proj outputs (2*DI)

typedef __attribute__((ext_vector_type(8))) __bf16 bf16x8;
typedef __attribute__((ext_vector_type(4))) float f32x4;
typedef __attribute__((ext_vector_type(2))) float f32x2;

__device__ __forceinline__ float siluf(float x) { return x / (1.f + __expf(-x)); }

__device__ __forceinline__ unsigned short f2bf(float f) {  // RNE, finite inputs
  unsigned int u = __float_as_uint(f);
  u = (u + 0x7fffu + ((u >> 16) & 1u)) >> 16;
  return (unsigned short)u;
}
__device__ __forceinline__ float bf2f(unsigned short h) {
  return __uint_as_float(((unsigned int)h) << 16);
}
__device__ __forceinline__ unsigned int pack2(float a, float b) {
  return (unsigned int)f2bf(a) | ((unsigned int)f2bf(b) << 16);
}

// sequence index l of direction k  ->  spatial position p (row-major h*56+w)
__device__ __forceinline__ int seq2pos(int k, int l) {
  int m = (k & 2) ? (LT - 1 - l) : l;
  return (k & 1) ? ((m % HW) * HW + m / HW) : m;
}

// Incremental position walker: uniform per-step update, no div/mod.
struct PosWalk {
  int p, cnt, wlim, winc, wstep, wadj, wrst;
  __device__ __forceinline__ void init(int k, int l0) {
    p = seq2pos(k, l0);
    if (k == 0)      { cnt = 0;  wlim = -9; winc = 0;  wstep = 1;   wadj = 0;     wrst = 0;  }
    else if (k == 1) { cnt = l0 % HW; wlim = HW - 1; winc = 1; wstep = HW; wadj = -(LT - HW - 1); wrst = 0; }
    else if (k == 2) { cnt = 0;  wlim = -9; winc = 0;  wstep = -1;  wadj = 0;     wrst = 0;  }
    else             { cnt = (LT - 1 - l0) % HW; wlim = 0; winc = -1; wstep = -HW; wadj = LT - HW - 1; wrst = HW - 1; }
  }
  __device__ __forceinline__ void next() {
    bool wrap = (cnt == wlim);
    p += wrap ? wadj : wstep;
    cnt = wrap ? wrst : cnt + winc;
  }
};

// ---------------- Kernel 0a: Wi -> bf16 ----------------
__global__ __launch_bounds__(256) void k_wiprep(const float* __restrict__ Wi,
                                                unsigned short* __restrict__ Wib) {
  int t = blockIdx.x * 256 + threadIdx.x;
  if (t >= NI * DM) return;
  Wib[t] = f2bf(Wi[t]);
}

// ---------------- Kernel 0b: Wp -> bf16, padded to 288 rows ----------------
__global__ __launch_bounds__(256) void k_wprep(const float* __restrict__ Wp,
                                               unsigned short* __restrict__ Wpb) {
  int t = blockIdx.x * 256 + threadIdx.x;
  if (t >= NOP * DI) return;
  int o = t / DI;
  Wpb[t] = (o < NO) ? f2bf(Wp[t]) : (unsigned short)0;
}

// ---------------- Kernel 0c: Wo -> transposed fp32 Wot[DI][DM] ----------------
__global__ __launch_bounds__(256) void k_woprep(const float* __restrict__ Wo,
                                                float* __restrict__ Wot) {
  int t = blockIdx.x * 256 + threadIdx.x;
  if (t >= DM * DI) return;
  int o = t / DI, j = t % DI;
  Wot[j * DM + o] = Wo[t];
}

// ---------------- Kernel 1: in_proj via bf16 MFMA + split + silu(z) ----------
__global__ __launch_bounds__(256) void k_inproj(const float* __restrict__ x,
                                                const unsigned short* __restrict__ Wib,
                                                float* __restrict__ xi,
                                                float* __restrict__ zs) {
  int wid = threadIdx.x >> 6;
  int lane = threadIdx.x & 63;
  int pos0 = blockIdx.x * 64 + wid * 16;
  int lrow = lane & 15;   // A: position-in-tile, B: output-in-tile
  int lgrp = lane >> 4;   // k-group (8 elements each)
  bf16x8 a[3];
  const float* arow = x + (size_t)(pos0 + lrow) * DM + lgrp * 8;
#pragma unroll
  for (int ks = 0; ks < 3; ks++) {
    f32x4 v0 = *reinterpret_cast<const f32x4*>(arow + ks * 32);
    f32x4 v1 = *reinterpret_cast<const f32x4*>(arow + ks * 32 + 4);
    union { unsigned short us[8]; bf16x8 v; } tmp;
#pragma unroll
    for (int j = 0; j < 4; j++) { tmp.us[j] = f2bf(v0[j]); tmp.us[4 + j] = f2bf(v1[j]); }
    a[ks] = tmp.v;
  }
  f32x4 acc[24];
#pragma unroll
  for (int t = 0; t < 24; t++) acc[t] = (f32x4){0.f, 0.f, 0.f, 0.f};
  const unsigned short* brow = Wib + (size_t)lrow * DM + lgrp * 8;
#pragma unroll
  for (int ks = 0; ks < 3; ks++) {
#pragma unroll
    for (int ot = 0; ot < 24; ot++) {
      bf16x8 bf = *reinterpret_cast<const bf16x8*>(brow + (size_t)ot * 16 * DM + ks * 32);
      acc[ot] = __builtin_amdgcn_mfma_f32_16x16x32_bf16(a[ks], bf, acc[ot], 0, 0, 0);
    }
  }
#pragma unroll
  for (int ot = 0; ot < 24; ot++) {
    int o = ot * 16 + lrow;
#pragma unroll
    for (int r = 0; r < 4; r++) {
      int pos = pos0 + lgrp * 4 + r;
      float v = acc[ot][r];
      if (o < DI) xi[(size_t)pos * DI + o] = v;
      else        zs[(size_t)pos * DI + (o - DI)] = siluf(v);
    }
  }
}

// ---------------- Kernel 2: depthwise 3x3 conv + bias + silu -> bf16 ----------
__global__ void k_conv(const float* __restrict__ xi, const float* __restrict__ cw,
                       const float* __restrict__ cb,
                       unsigned short* __restrict__ xcb) {
  int t = blockIdx.x * 256 + threadIdx.x;
  if (t >= NPOS * DI) return;
  int c = t % DI;
  int pos = t / DI;
  int p = pos % LT, b = pos / LT;
  int h = p / HW, w = p % HW;
  float acc = cb[c];
#pragma unroll
  for (int dh = 0; dh < 3; dh++) {
    int hh = h + dh - 1;
    if (hh < 0 || hh >= HW) continue;
#pragma unroll
    for (int dw = 0; dw < 3; dw++) {
      int ww = w + dw - 1;
      if (ww < 0 || ww >= HW) continue;
      acc += cw[(dh * 3 + dw) * DI + c] * xi[(b * LT + hh * HW + ww) * DI + c];
    }
  }
  xcb[t] = f2bf(siluf(acc));
}

// ---------------- Kernel 3: x_proj via bf16 MFMA + softplus/exp ----------------
__global__ __launch_bounds__(128) void k_xproj(const unsigned short* __restrict__ xcb,
                                               const unsigned short* __restrict__ Wpb,
                                               const float* __restrict__ A_logs,
                                               const float* __restrict__ dt_bias,
                                               float* __restrict__ dtb,
                                               float* __restrict__ dAb,
                                               float* __restrict__ Bsb,
                                               float* __restrict__ Csb) {
  int wid = threadIdx.x >> 6;
  int lane = threadIdx.x & 63;
  int pos0 = blockIdx.x * 32 + wid * 16;
  int lrow = lane & 15;   // A: position-in-tile, B: output-in-tile
  int lgrp = lane >> 4;   // k-group (8 bf16 each)
  bf16x8 a[6];
  const unsigned short* arow = xcb + (size_t)(pos0 + lrow) * DI + lgrp * 8;
#pragma unroll
  for (int ks = 0; ks < 6; ks++)
    a[ks] = *reinterpret_cast<const bf16x8*>(arow + ks * 32);
  f32x4 acc[18];
#pragma unroll
  for (int t = 0; t < 18; t++) acc[t] = (f32x4){0.f, 0.f, 0.f, 0.f};
  const unsigned short* brow = Wpb + (size_t)lrow * DI + lgrp * 8;
#pragma unroll
  for (int ks = 0; ks < 6; ks++) {
#pragma unroll
    for (int ot = 0; ot < 18; ot++) {
      bf16x8 bf = *reinterpret_cast<const bf16x8*>(brow + (size_t)ot * 16 * DI + ks * 32);
      acc[ot] = __builtin_amdgcn_mfma_f32_16x16x32_bf16(a[ks], bf, acc[ot], 0, 0, 0);
    }
  }
#pragma unroll
  for (int ot = 0; ot < 18; ot++) {
    int o = ot * 16 + lrow;
    if (o >= NO) continue;
    int k = o / 70, c = o % 70;
#pragma unroll
    for (int r = 0; r < 4; r++) {
      int pos = pos0 + lgrp * 4 + r;
      float v = acc[ot][r];
      int base = pos * KD + k;
      if (c < RK) {
        float bias = dt_bias[k * RK + c];
        float Av = -__expf(A_logs[k * RK + c]);
        float s = v + bias;
        float dtv = (s > 20.f) ? s : log1pf(__expf(s));
        dtb[base * RK + c] = dtv;
        dAb[base * RK + c] = __expf(dtv * Av);
      } else if (c < RK + NS) {
        Bsb[base * NS + (c - RK)] = v;
      } else {
        Csb[base * NS + (c - RK - NS)] = v;
      }
    }
  }
}

// ---------------- Kernel 4: states-only local scan (packed fp32, bf16 x) -------
__global__ __launch_bounds__(192) void k_scanA(const unsigned short* __restrict__ xcb,
                                               const float* __restrict__ dtb,
                                               const float* __restrict__ dAb,
                                               const float* __restrict__ Bsb,
                                               unsigned short* __restrict__ Send,
                                               float* __restrict__ Pend) {
  int bi = blockIdx.x;
  int chunk = bi % NC;
  int k = (bi / NC) & 3;
  int b = bi / (NC * KD);
  int seq = b * KD + k;
  int tid = threadIdx.x;
  int r = tid >> 5, d = tid & 31;
  f32x2 S2[16];
#pragma unroll
  for (int i = 0; i < 16; i++) S2[i] = (f32x2){0.f, 0.f};
  float cum = 1.f;
  PosWalk pw; pw.init(k, chunk * CH);
  const unsigned short* xp = xcb + (size_t)b * LT * DI + tid;
  size_t cb0 = (size_t)b * LT * KD + k;
  for (int l = 0; l < CH; l++) {
    size_t base = cb0 + (size_t)pw.p * KD;      // block-uniform
    const f32x4* Bp = reinterpret_cast<const f32x4*>(Bsb + base * NS);
    f32x4 bv[8];
#pragma unroll
    for (int i = 0; i < 8; i++) bv[i] = Bp[i];
    float dAr = dAb[base * RK + r];
    float dtr = dtb[base * RK + r];
    float xv = bf2f(xp[(size_t)pw.p * DI]);
    float xdt = xv * dtr;
    f32x2 dA2 = {dAr, dAr}, xd2 = {xdt, xdt};
#pragma unroll
    for (int i = 0; i < 8; i++) {
      f32x2 bl = __builtin_shufflevector(bv[i], bv[i], 0, 1);
      f32x2 bh = __builtin_shufflevector(bv[i], bv[i], 2, 3);
      S2[2 * i]     = S2[2 * i] * dA2 + xd2 * bl;
      S2[2 * i + 1] = S2[2 * i + 1] * dA2 + xd2 * bh;
    }
    cum *= dAr;
    pw.next();
  }
  unsigned int* dst = (unsigned int*)(Send + (size_t)(seq * NC + chunk) * ELEM + tid * NS);
#pragma unroll
  for (int i = 0; i < 16; i++) dst[i] = pack2(S2[i][0], S2[i][1]);
  if (d == 0) Pend[(seq * NC + chunk) * RK + r] = cum;
}

// ---------------- Kernel 5: chunk-state combine (bf16 in-place excl. prefix) ----
__global__ __launch_bounds__(256) void k_scanB(unsigned int* __restrict__ Send32,
                                               const float* __restrict__ Pend) {
  const int EU = ELEM / 2;           // 3072 uints per (seq,chunk)
  int bi = blockIdx.x;               // 32 seqs * 12 uint-tiles
  int seq = bi / (EU / 256);
  int u = (bi % (EU / 256)) * 256 + threadIdx.x;
  int r = u >> 9;                    // element e = 2u, r = e>>10
  float run0 = 0.f, run1 = 0.f;
  for (int c = 0; c < NC; c++) {
    size_t idx = (size_t)(seq * NC + c) * EU + u;
    unsigned int v = Send32[idx];
    float t0 = bf2f((unsigned short)(v & 0xffff));
    float t1 = bf2f((unsigned short)(v >> 16));
    Send32[idx] = pack2(run0, run1);
    float pe = Pend[(seq * NC + c) * RK + r];
    run0 = run0 * pe + t0;
    run1 = run1 * pe + t1;
  }
}

// ---------------- Kernel 6: full scan recompute, bf16 x in, bf16 y out ---------
__global__ __launch_bounds__(192) void k_scanD(const unsigned short* __restrict__ xcb,
                                               const float* __restrict__ dtb,
                                               const float* __restrict__ dAb,
                                               const float* __restrict__ Bsb,
                                               const float* __restrict__ Csb,
                                               const float* __restrict__ Ds,
                                               const unsigned short* __restrict__ Sinit,
                                               unsigned short* __restrict__ ybh) {
  int bi = blockIdx.x;
  int chunk = bi % NC;
  int k = (bi / NC) & 3;
  int b = bi / (NC * KD);
  int seq = b * KD + k;
  int tid = threadIdx.x;
  int r = tid >> 5, d = tid & 31;
  f32x2 S2[16];
  const unsigned int* sp = (const unsigned int*)(Sinit + (size_t)(seq * NC + chunk) * ELEM + tid * NS);
#pragma unroll
  for (int i = 0; i < 16; i++) {
    unsigned int v = sp[i];
    S2[i] = (f32x2){bf2f((unsigned short)(v & 0xffff)), bf2f((unsigned short)(v >> 16))};
  }
  float Dsv = Ds[(k * RK + r) * NS + d];
  PosWalk pw; pw.init(k, chunk * CH);
  const unsigned short* xp = xcb + (size_t)b * LT * DI + tid;
  unsigned short* yb = ybh + (size_t)seq * LT * DI + tid;
  size_t cb0 = (size_t)b * LT * KD + k;
  for (int l = 0; l < CH; l++) {
    size_t base = cb0 + (size_t)pw.p * KD;      // block-uniform
    const f32x4* Bp = reinterpret_cast<const f32x4*>(Bsb + base * NS);
    const f32x4* Cp = reinterpret_cast<const f32x4*>(Csb + base * NS);
    f32x4 bv[8], cv[8];
#pragma unroll
    for (int i = 0; i < 8; i++) { bv[i] = Bp[i]; cv[i] = Cp[i]; }
    float dAr = dAb[base * RK + r];
    float dtr = dtb[base * RK + r];
    float xv = bf2f(xp[(size_t)pw.p * DI]);
    float xdt = xv * dtr;
    f32x2 dA2 = {dAr, dAr}, xd2 = {xdt, xdt};
    f32x2 y2 = {0.f, 0.f};
#pragma unroll
    for (int i = 0; i < 8; i++) {
      f32x2 bl = __builtin_shufflevector(bv[i], bv[i], 0, 1);
      f32x2 bh = __builtin_shufflevector(bv[i], bv[i], 2, 3);
      f32x2 cl = __builtin_shufflevector(cv[i], cv[i], 0, 1);
      f32x2 ch = __builtin_shufflevector(cv[i], cv[i], 2, 3);
      S2[2 * i]     = S2[2 * i] * dA2 + xd2 * bl;
      y2 += S2[2 * i] * cl;
      S2[2 * i + 1] = S2[2 * i + 1] * dA2 + xd2 * bh;
      y2 += S2[2 * i + 1] * ch;
    }
    yb[(size_t)pw.p * DI] = f2bf(y2[0] + y2[1] + xv * Dsv);
    pw.next();
  }
}

// ---------------- Kernel 7: merge + LN + gelu + *silu(z) + out_proj ----------------
__global__ __launch_bounds__(192) void k_out(const unsigned short* __restrict__ ybh,
                                             const float* __restrict__ zs,
                                             const float* __restrict__ ln_g,
                                             const float* __restrict__ ln_b,
                                             const float* __restrict__ Wot,
                                             float* __restrict__ out) {
  const int PP = 4;
  int pos0 = blockIdx.x * PP;
  int b = pos0 / LT, p0 = pos0 % LT;
  int tid = threadIdx.x;  // 0..191 = channel
  float v[PP], s1[PP], s2[PP];
#pragma unroll
  for (int q = 0; q < PP; q++) {
    float acc = 0.f;
#pragma unroll
    for (int k = 0; k < KD; k++)
      acc += bf2f(ybh[((size_t)(b * KD + k) * LT + p0 + q) * DI + tid]);
    v[q] = acc; s1[q] = acc; s2[q] = acc * acc;
  }
#pragma unroll
  for (int off = 32; off; off >>= 1) {
#pragma unroll
    for (int q = 0; q < PP; q++) {
      s1[q] += __shfl_down(s1[q], off, 64);
      s2[q] += __shfl_down(s2[q], off, 64);
    }
  }
  __shared__ float rs1[3][PP], rs2[3][PP];
  int wave = tid >> 6, lane = tid & 63;
  if (lane == 0) {
#pragma unroll
    for (int q = 0; q < PP; q++) { rs1[wave][q] = s1[q]; rs2[wave][q] = s2[q]; }
  }
  __syncthreads();
  __shared__ float su[PP][DI];
  float g = ln_g[tid], be = ln_b[tid];
#pragma unroll
  for (int q = 0; q < PP; q++) {
    float mean = (rs1[0][q] + rs1[1][q] + rs1[2][q]) * (1.f / 192.f);
    float var = (rs2[0][q] + rs2[1][q] + rs2[2][q]) * (1.f / 192.f) - mean * mean;
    float rstd = rsqrtf(var + 1e-5f);
    float t = (v[q] - mean) * rstd * g + be;
    float ge = 0.5f * t * (1.f + erff(t * 0.70710678118f));
    su[q][tid] = ge * zs[(pos0 + q) * DI + tid];
  }
  __syncthreads();
  int o = tid % DM, half = tid / DM;  // 2 threads per output column
  const float* wcol = Wot + (size_t)half * DM * DM + o;
  float acc[PP];
#pragma unroll
  for (int q = 0; q < PP; q++) acc[q] = 0.f;
  for (int j = 0; j < DM; j++) {
    float w = wcol[(size_t)j * DM];   // lane-coalesced
#pragma unroll
    for (int q = 0; q < PP; q++) acc[q] += w * su[q][half * DM + j];
  }
  __shared__ float part[PP][DI];
#pragma unroll
  for (int q = 0; q < PP; q++) part[q][tid] = acc[q];
  __syncthreads();
  if (tid < DM) {
#pragma unroll
    for (int q = 0; q < PP; q++)
      out[(pos0 + q) * DM + tid] = part[q][tid] + part[q][tid + DM];
  }
}

extern "C" void kernel_launch(void* const* d_in, const int* in_sizes, int n_in,
                              void* d_out, int out_size, void* d_ws, size_t ws_size,
                              hipStream_t stream) {
  const float* x       = (const float*)d_in[0];
  const float* Wi      = (const float*)d_in[1];
  const float* cw      = (const float*)d_in[2];
  const float* cb      = (const float*)d_in[3];
  const float* Wp      = (const float*)d_in[4];
  const float* Ds      = (const float*)d_in[5];
  const float* A_logs  = (const float*)d_in[6];
  const float* dt_bias = (const float*)d_in[7];
  const float* ln_g    = (const float*)d_in[8];
  const float* ln_b    = (const float*)d_in[9];
  const float* Wo      = (const float*)d_in[10];
  float* out = (float*)d_out;

  float* ws = (float*)d_ws;
  float* xi    = ws;                       // NPOS*DI f32
  float* zs    = xi + (size_t)NPOS * DI;   // NPOS*DI f32
  float* dtb   = zs + (size_t)NPOS * DI;   // NPOS*KD*RK f32
  float* dAb   = dtb + (size_t)NPOS * KD * RK;
  float* Bsb   = dAb + (size_t)NPOS * KD * RK;   // NPOS*KD*NS f32
  float* Csb   = Bsb + (size_t)NPOS * KD * NS;
  unsigned short* xcb  = (unsigned short*)(Csb + (size_t)NPOS * KD * NS); // NPOS*DI bf16
  unsigned short* ybh  = xcb + (size_t)NPOS * DI;                          // NPOS*KD*DI bf16
  unsigned short* Send = ybh + (size_t)NPOS * KD * DI;                     // SEQ*NC*ELEM bf16
  float* Pend  = (float*)(Send + (size_t)SEQ * NC * ELEM);  // SEQ*NC*RK f32
  float* WpbF  = Pend + (size_t)SEQ * NC * RK;
  float* WibF  = WpbF + (size_t)NOP * DI / 2;
  float* Wot   = WibF + (size_t)NI * DM / 2;                // DI*DM f32
  unsigned short* Wpb = (unsigned short*)WpbF;
  unsigned short* Wib = (unsigned short*)WibF;

  k_wiprep<<<(NI * DM + 255) / 256, 256, 0, stream>>>(Wi, Wib);
  k_wprep<<<(NOP * DI + 255) / 256, 256, 0, stream>>>(Wp, Wpb);
  k_woprep<<<(DM * DI + 255) / 256, 256, 0, stream>>>(Wo, Wot);
  k_inproj<<<NPOS / 64, 256, 0, stream>>>(x, Wib, xi, zs);
  k_conv<<<(NPOS * DI + 255) / 256, 256, 0, stream>>>(xi, cw, cb, xcb);
  k_xproj<<<NPOS / 32, 128, 0, stream>>>(xcb, Wpb, A_logs, dt_bias, dtb, dAb, Bsb, Csb);
  k_scanA<<<NB * KD * NC, 192, 0, stream>>>(xcb, dtb, dAb, Bsb, Send, Pend);
  k_scanB<<<SEQ * (ELEM / 512), 256, 0, stream>>>((unsigned int*)Send, Pend);
  k_scanD<<<NB * KD * NC, 192, 0, stream>>>(xcb, dtb, dAb, Bsb, Csb, Ds, Send, ybh);
  k_out<<<NPOS / 4, 192, 0, stream>>>(ybh, zs, ln_g, ln_b, Wot, out);
}